// Round 2
// baseline (1346.377 us; speedup 1.0000x reference)
//
#include <hip/hip_runtime.h>
#include <stdint.h>

#define DEV static __device__ __forceinline__

typedef unsigned short u16;
typedef __attribute__((ext_vector_type(8))) short v8s;    // 8 x bf16 MFMA operand
typedef __attribute__((ext_vector_type(4))) float v4f;
typedef __attribute__((ext_vector_type(4))) unsigned short v4u16;

DEV u16 f2bf(float f) {
  union { float f; unsigned u; } c; c.f = f;
  unsigned r = c.u + 0x7FFFu + ((c.u >> 16) & 1u);
  return (u16)(r >> 16);
}
DEV float bf2f(u16 h) {
  union { unsigned u; float f; } c; c.u = ((unsigned)h) << 16;
  return c.f;
}

// async global->LDS, 16B per lane; LDS dest = wave-uniform base + lane*16.
DEV void gload16(const u16* g, u16* l) {
  __builtin_amdgcn_global_load_lds(
      (const __attribute__((address_space(1))) unsigned int*)g,
      (__attribute__((address_space(3))) unsigned int*)l, 16, 0, 0);
}

enum { MODE_QKV = 0, MODE_SCORE = 1, MODE_PV = 2, MODE_BIAS_RES = 3, MODE_BIAS_RELU = 4 };

struct EpArgs {
  const unsigned char* mask;  // SCORE
  const int* mask_flag;       // SCORE: 1 -> int32 mask, 0 -> byte mask
  const float* bias;          // BIAS_*
  const float* res;           // BIAS_RES fp32 residual (or null)
  const u16* res_bf;          // BIAS_RES bf16 residual (used if res==null)
  float* outf;                // BIAS_RES
  u16* outb;                  // SCORE/PV/BIAS_RELU
  u16* q; u16* k; u16* v;     // QKV scatter (v stored transposed [z,e,s])
  int z0;                     // chunk base z for SCORE/PV
};

// NT GEMM: C[m][n] = sum_k A[m][k]*B[n][k]. BK=32, 256 thr = 4 waves (2x2).
template <int BM, int BN, int FM, int FN, int MODE>
__global__ __launch_bounds__(256, 2)
void gemm_nt(const u16* __restrict__ A, int lda, long sA,
             const u16* __restrict__ B, int ldb, long sB,
             int K, int N, EpArgs ep)
{
  __shared__ u16 As[BM * 32];
  __shared__ u16 Bs[BN * 32];

  const int tid  = threadIdx.x;
  const int lane = tid & 63;
  const int wave = tid >> 6;
  const int wm = (wave >> 1) * (FM * 16);
  const int wn = (wave & 1) * (FN * 16);
  const int tm = blockIdx.y * BM;
  const int tn = blockIdx.x * BN;
  const int z  = blockIdx.z;

  const u16* Az = A + (long)z * sA;
  const u16* Bz = B + (long)z * sB;

  v4f acc[FM][FN];
  const v4f zero4 = {0.f, 0.f, 0.f, 0.f};
#pragma unroll
  for (int i = 0; i < FM; i++)
#pragma unroll
    for (int j = 0; j < FN; j++) acc[i][j] = zero4;

  for (int kt = 0; kt < K; kt += 32) {
#pragma unroll
    for (int c = 0; c < BM * 4; c += 256) {
      int cc = c + tid;
      int row = cc >> 2, kk = (cc & 3) * 8;
      gload16(Az + (long)(tm + row) * lda + kt + kk, &As[cc * 8]);
    }
#pragma unroll
    for (int c = 0; c < BN * 4; c += 256) {
      int cc = c + tid;
      int row = cc >> 2, kk = (cc & 3) * 8;
      gload16(Bz + (long)(tn + row) * ldb + kt + kk, &Bs[cc * 8]);
    }
    __syncthreads();  // drains vmcnt for global_load_lds

    v8s af[FM], bfr[FN];
#pragma unroll
    for (int i = 0; i < FM; i++)
      af[i] = *(const v8s*)&As[(wm + i * 16 + (lane & 15)) * 32 + (lane >> 4) * 8];
#pragma unroll
    for (int j = 0; j < FN; j++)
      bfr[j] = *(const v8s*)&Bs[(wn + j * 16 + (lane & 15)) * 32 + (lane >> 4) * 8];
#pragma unroll
    for (int i = 0; i < FM; i++)
#pragma unroll
      for (int j = 0; j < FN; j++)
        acc[i][j] = __builtin_amdgcn_mfma_f32_16x16x32_bf16(af[i], bfr[j], acc[i][j], 0, 0, 0);
    __syncthreads();
  }

  bool mflag = false;
  if constexpr (MODE == MODE_SCORE) mflag = (*ep.mask_flag != 0);
  bool res_is_f32 = false;
  if constexpr (MODE == MODE_BIAS_RES) res_is_f32 = (ep.res != nullptr);

  // C/D layout (m89/m91-verified): col = lane&15, row = (lane>>4)*4 + r
#pragma unroll
  for (int i = 0; i < FM; i++) {
    int mbase = tm + wm + i * 16 + ((lane >> 4) << 2);
#pragma unroll
    for (int j = 0; j < FN; j++) {
      int n = tn + wn + j * 16 + (lane & 15);
#pragma unroll
      for (int r = 0; r < 4; r++) {
        float val = acc[i][j][r];
        int m = mbase + r;
        if constexpr (MODE == MODE_QKV) {
          int b = m >> 10, s = m & 1023;
          int w = n >> 10, rr = n & 1023, h = rr >> 6, e = rr & 63;
          u16 bv = f2bf(val);
          if (w == 2) {
            ep.v[((long)(b * 16 + h) << 16) + e * 1024 + s] = bv;  // V^T [z,e,s]
          } else {
            long idx = (((long)(b * 16 + h) << 10) + s) * 64 + e;  // [z,s,e]
            if (w == 0) ep.q[idx] = bv; else ep.k[idx] = bv;
          }
        } else if constexpr (MODE == MODE_SCORE) {
          int zg = ep.z0 + z;
          int b = zg >> 4;
          long idx = (long)m * 1024 + n;
          bool mk = mflag ? (((const int*)ep.mask)[(long)b * 1048576 + idx] != 0)
                          : (ep.mask[(long)b * 1048576 + idx] != 0);
          float sv = mk ? val : -1000.0f;       // mask BEFORE scale (ref quirk)
          ep.outb[((long)z << 20) + idx] = f2bf(__expf(sv * 0.125f));
        } else if constexpr (MODE == MODE_PV) {
          int zg = ep.z0 + z;
          int b = zg >> 4, h = zg & 15;
          ep.outb[((long)(b * 1024 + m) << 10) + h * 64 + n] = f2bf(val);
        } else if constexpr (MODE == MODE_BIAS_RES) {
          long idx = (long)m * N + n;
          float rres = res_is_f32 ? ep.res[idx] : bf2f(ep.res_bf[idx]);
          ep.outf[idx] = val + ep.bias[n] + rres;
        } else if constexpr (MODE == MODE_BIAS_RELU) {
          float v2 = val + ep.bias[n];
          ep.outb[(long)m * N + n] = f2bf(fmaxf(v2, 0.f));
        }
      }
    }
  }
}

// LayerNorm over 1024 cols; one block per row.
__global__ __launch_bounds__(256)
void ln_kernel(const float* __restrict__ in, const float* __restrict__ gam,
               const float* __restrict__ bet, float* __restrict__ outf,
               u16* __restrict__ outb)
{
  long row = blockIdx.x;
  v4f v = *(const v4f*)(in + (row << 10) + (threadIdx.x << 2));
  float s = v.x + v.y + v.z + v.w;
  float s2 = v.x * v.x + v.y * v.y + v.z * v.z + v.w * v.w;
#pragma unroll
  for (int o = 32; o > 0; o >>= 1) { s += __shfl_down(s, o); s2 += __shfl_down(s2, o); }
  __shared__ float red[8];
  int wv_ = threadIdx.x >> 6, ln = threadIdx.x & 63;
  if (ln == 0) { red[wv_] = s; red[4 + wv_] = s2; }
  __syncthreads();
  float S1 = red[0] + red[1] + red[2] + red[3];
  float S2 = red[4] + red[5] + red[6] + red[7];
  float mu = S1 * (1.f / 1024.f);
  float var = S2 * (1.f / 1024.f) - mu * mu;
  float rstd = rsqrtf(var + 1e-5f);
  v4f g4 = *(const v4f*)(gam + (threadIdx.x << 2));
  v4f b4 = *(const v4f*)(bet + (threadIdx.x << 2));
  v4f o4;
  o4.x = (v.x - mu) * rstd * g4.x + b4.x;
  o4.y = (v.y - mu) * rstd * g4.y + b4.y;
  o4.z = (v.z - mu) * rstd * g4.z + b4.z;
  o4.w = (v.w - mu) * rstd * g4.w + b4.w;
  if (outf) *(v4f*)(outf + (row << 10) + (threadIdx.x << 2)) = o4;
  if (outb) {
    v4u16 u;
    u.x = f2bf(o4.x); u.y = f2bf(o4.y); u.z = f2bf(o4.z); u.w = f2bf(o4.w);
    *(v4u16*)(outb + (row << 10) + (threadIdx.x << 2)) = u;
  }
}

// Chunk-local: per (zl,k) column sums of E over q -> reciprocal. grid (4, CZ).
__global__ __launch_bounds__(256)
void colsum_recip(const u16* __restrict__ E, float* __restrict__ rc)
{
  int k = blockIdx.x * 256 + threadIdx.x;
  int z = blockIdx.y;
  const u16* e = E + ((long)z << 20) + k;
  float s = 0.f;
#pragma unroll 8
  for (int q = 0; q < 1024; q++) s += bf2f(e[(long)q << 10]);
  rc[(z << 10) + k] = 1.f / s;
}

// Chunk-local: scale V^T rows by rc. i = zl*65536 + e*1024 + s.
__global__ __launch_bounds__(256)
void scale_v(u16* __restrict__ vT, const float* __restrict__ rc)
{
  long i = (long)blockIdx.x * 256 + threadIdx.x;
  int zl = (int)(i >> 16);
  int spos = (int)(i & 1023);
  vT[i] = f2bf(bf2f(vT[i]) * rc[(zl << 10) + spos]);
}

__global__ __launch_bounds__(256)
void cvt_bf16(const float* __restrict__ in, u16* __restrict__ out, int n4)
{
  int i = blockIdx.x * 256 + threadIdx.x;
  if (i >= n4) return;
  v4f v = ((const v4f*)in)[i];
  v4u16 u;
  u.x = f2bf(v.x); u.y = f2bf(v.y); u.z = f2bf(v.z); u.w = f2bf(v.w);
  ((v4u16*)out)[i] = u;
}

// Pack wq/wk/wv [h][d][e] -> B matrix [n = w*1024 + h*64 + e][d] bf16.
__global__ __launch_bounds__(256)
void pack_qkvw(const float* __restrict__ wq, const float* __restrict__ wk,
               const float* __restrict__ wv, u16* __restrict__ out)
{
  int i = blockIdx.x * 256 + threadIdx.x;  // 3*2^20 total
  int w = i >> 20, r = i & 1048575;
  int e = r & 63, d = (r >> 6) & 1023, h = r >> 16;
  const float* src = (w == 0) ? wq : ((w == 1) ? wk : wv);
  float v = src[(((long)h << 10) + d) * 64 + e];
  out[((((long)w << 10) + (h << 6) + e) << 10) + d] = f2bf(v);
}

// Detect whether mask is int32 (bytes at i%4!=0 all zero) or bool bytes.
__global__ void detect_mask_kernel(const unsigned char* __restrict__ m, int* __restrict__ flag)
{
  if (threadIdx.x == 0 && blockIdx.x == 0) {
    int nz = 0;
    for (int i = 0; i < 256; i++)
      if ((i & 3) != 0 && m[i] != 0) nz++;
    *flag = (nz == 0) ? 1 : 0;
  }
}

extern "C" void kernel_launch(void* const* d_in, const int* in_sizes, int n_in,
                              void* d_out, int out_size, void* d_ws, size_t ws_size,
                              hipStream_t stream)
{
  const float* x     = (const float*)d_in[0];
  const unsigned char* mask = (const unsigned char*)d_in[1];
  const float* wq    = (const float*)d_in[2];
  const float* wk    = (const float*)d_in[3];
  const float* wv    = (const float*)d_in[4];
  const float* fc_w  = (const float*)d_in[5];
  const float* fc_b  = (const float*)d_in[6];
  const float* w1    = (const float*)d_in[7];
  const float* b1    = (const float*)d_in[8];
  const float* w2    = (const float*)d_in[9];
  const float* b2    = (const float*)d_in[10];
  const float* ln1_g = (const float*)d_in[11];
  const float* ln1_b = (const float*)d_in[12];
  const float* ln2_g = (const float*)d_in[13];
  const float* ln2_b = (const float*)d_in[14];
  (void)in_sizes; (void)n_in; (void)out_size; (void)ws_size;

  // ---- workspace map: peak 137 MB (explicit lifetimes, aliased) ----
  const size_t MB = 1ull << 20;
  char* ws = (char*)d_ws;
  int*   mflag = (int*)ws;                  // [0, 4)
  float* rc    = (float*)(ws + 4096);       // 64 KB used (chunk-local)
  u16*   bqkv  = (u16*)(ws + 1 * MB);       // 6 MB  [1,7)
  u16*   fcb   = (u16*)(ws + 7 * MB);       // 2 MB  [7,9)
  u16*   w1b   = (u16*)(ws + 9 * MB);       // 8 MB  [9,17)
  u16*   w2b   = (u16*)(ws + 17 * MB);      // 8 MB  [17,25)
  u16*   xb    = (u16*)(ws + 25 * MB);      // 16 MB [25,41)  -> x1b later
  u16*   x1b   = xb;
  u16*   Qb    = (u16*)(ws + 41 * MB);      // 16 MB [41,57)
  u16*   Kb    = (u16*)(ws + 57 * MB);      // 16 MB [57,73)
  u16*   vT    = (u16*)(ws + 73 * MB);      // 16 MB [73,89)
  u16*   oc    = (u16*)(ws + 89 * MB);      // 16 MB [89,105)
  u16*   h1    = (u16*)(ws + 41 * MB);      // 64 MB [41,105) alias (post-attn)
  float* r1    = (float*)(ws + 105 * MB);   // 32 MB [105,137)
  u16*   Ech   = (u16*)(ws + 105 * MB);     // 32 MB alias r1 (attn phase only)

  detect_mask_kernel<<<1, 64, 0, stream>>>(mask, mflag);

  cvt_bf16<<<8192, 256, 0, stream>>>(x, xb, 2097152);
  pack_qkvw<<<12288, 256, 0, stream>>>(wq, wk, wv, bqkv);
  cvt_bf16<<<1024, 256, 0, stream>>>(fc_w, fcb, 262144);
  cvt_bf16<<<4096, 256, 0, stream>>>(w1, w1b, 1048576);
  cvt_bf16<<<4096, 256, 0, stream>>>(w2, w2b, 1048576);

  // QKV projections: [8192 x 1024] x [3072 x 1024]^T
  {
    EpArgs ep = {};
    ep.q = Qb; ep.k = Kb; ep.v = vT;
    gemm_nt<128, 128, 4, 4, MODE_QKV><<<dim3(24, 64, 1), 256, 0, stream>>>(
        xb, 1024, 0, bqkv, 1024, 0, 1024, 3072, ep);
  }

  // Attention in chunks of CZ=16 (b,h)-slices; E-chunk = 32 MB (aliases r1).
  const int CZ = 16;
  for (int z0 = 0; z0 < 128; z0 += CZ) {
    {
      EpArgs ep = {};
      ep.mask = mask; ep.mask_flag = mflag; ep.outb = Ech; ep.z0 = z0;
      gemm_nt<128, 128, 4, 4, MODE_SCORE><<<dim3(8, 8, CZ), 256, 0, stream>>>(
          Qb + (long)z0 * 65536, 64, 65536,
          Kb + (long)z0 * 65536, 64, 65536, 64, 1024, ep);
    }
    colsum_recip<<<dim3(4, CZ), 256, 0, stream>>>(Ech, rc);
    scale_v<<<CZ * 256, 256, 0, stream>>>(vT + (long)z0 * 65536, rc);
    {
      EpArgs ep = {};
      ep.outb = oc; ep.z0 = z0;
      gemm_nt<64, 64, 2, 2, MODE_PV><<<dim3(1, 16, CZ), 256, 0, stream>>>(
          Ech, 1024, 1048576,
          vT + (long)z0 * 65536, 1024, 65536, 1024, 64, ep);
    }
  }

  // att = oc @ fc_w^T + fc_b + x -> r1 (fp32)
  {
    EpArgs ep = {};
    ep.bias = fc_b; ep.res = x; ep.outf = r1;
    gemm_nt<128, 128, 4, 4, MODE_BIAS_RES><<<dim3(8, 64, 1), 256, 0, stream>>>(
        oc, 1024, 0, fcb, 1024, 0, 1024, 1024, ep);
  }
  ln_kernel<<<8192, 256, 0, stream>>>(r1, ln1_g, ln1_b, (float*)nullptr, x1b);
  // h1 = relu(x1 @ w1^T + b1) bf16
  {
    EpArgs ep = {};
    ep.bias = b1; ep.outb = h1;
    gemm_nt<128, 128, 4, 4, MODE_BIAS_RELU><<<dim3(32, 64, 1), 256, 0, stream>>>(
        x1b, 1024, 0, w1b, 1024, 0, 1024, 4096, ep);
  }
  // r2 = h1 @ w2^T + b2 + x1(bf16) -> r1 (fp32)
  {
    EpArgs ep = {};
    ep.bias = b2; ep.res_bf = x1b; ep.outf = r1;
    gemm_nt<128, 128, 4, 4, MODE_BIAS_RES><<<dim3(8, 64, 1), 256, 0, stream>>>(
        h1, 4096, 0, w2b, 4096, 0, 4096, 1024, ep);
  }
  ln_kernel<<<8192, 256, 0, stream>>>(r1, ln2_g, ln2_b, (float*)d_out, (u16*)nullptr);
}

// Round 3
// 998.259 us; speedup vs baseline: 1.3487x; 1.3487x over previous
//
#include <hip/hip_runtime.h>
#include <stdint.h>

#define DEV static __device__ __forceinline__

typedef unsigned short u16;
typedef __attribute__((ext_vector_type(8))) short v8s;    // 8 x bf16 MFMA operand
typedef __attribute__((ext_vector_type(4))) float v4f;
typedef __attribute__((ext_vector_type(4))) unsigned short v4u16;

DEV u16 f2bf(float f) {
  union { float f; unsigned u; } c; c.f = f;
  unsigned r = c.u + 0x7FFFu + ((c.u >> 16) & 1u);
  return (u16)(r >> 16);
}
DEV float bf2f(u16 h) {
  union { unsigned u; float f; } c; c.u = ((unsigned)h) << 16;
  return c.f;
}

// async global->LDS, 16B per lane; LDS dest = wave-uniform base + lane*16.
DEV void gload16(const u16* g, u16* l) {
  __builtin_amdgcn_global_load_lds(
      (const __attribute__((address_space(1))) unsigned int*)g,
      (__attribute__((address_space(3))) unsigned int*)l, 16, 0, 0);
}

enum { MODE_QKV = 0, MODE_SCORE = 1, MODE_PV = 2, MODE_BIAS_RES = 3, MODE_BIAS_RELU = 4 };

struct EpArgs {
  const unsigned char* mask;  // SCORE
  const int* mask_flag;       // SCORE: 1 -> int32 mask, 0 -> byte mask
  const float* bias;          // BIAS_*
  const float* res;           // BIAS_RES fp32 residual (or null)
  const u16* res_bf;          // BIAS_RES bf16 residual (used if res==null)
  float* outf;                // BIAS_RES
  u16* outb;                  // SCORE/PV/BIAS_RELU
  u16* q; u16* k; u16* v;     // QKV scatter (all [z,s,e] now)
  float* rcsum;               // SCORE: per-(zl,k) column-sum accumulators (pre-zeroed)
  int z0;                     // chunk base z for SCORE/PV
};

// NT GEMM: C[m][n] = sum_k A[m][k]*B[n][k]. BK=32, 256 thr = 4 waves (2x2).
// Tiles flattened into grid.x with XCD-aware swizzle: same-XCD blocks (id%8)
// share a group of 8 A row-blocks -> per-XCD L2 reuse. z = blockIdx.y.
template <int BM, int BN, int FM, int FN, int MODE>
__global__ __launch_bounds__(256, 2)
void gemm_nt(const u16* __restrict__ A, int lda, long sA,
             const u16* __restrict__ B, int ldb, long sB,
             int K, int N, int nbx, int nby, EpArgs ep)
{
  __shared__ u16 As[BM * 32];
  __shared__ u16 Bs[BN * 32];

  const int tid  = threadIdx.x;
  const int lane = tid & 63;
  const int wave = tid >> 6;
  const int wm = (wave >> 1) * (FM * 16);
  const int wn = (wave & 1) * (FN * 16);

  // XCD swizzle (nby must be a multiple of 8)
  const int id = blockIdx.x;
  const int nby8 = nby >> 3;
  const int c8 = id & 7, jj = id >> 3;
  const int tm = ((jj % nby8) * 8 + c8) * BM;
  const int tn = (jj / nby8) * BN;
  const int z  = blockIdx.y;

  const u16* Az = A + (long)z * sA;
  const u16* Bz = B + (long)z * sB;

  v4f acc[FM][FN];
  const v4f zero4 = {0.f, 0.f, 0.f, 0.f};
#pragma unroll
  for (int i = 0; i < FM; i++)
#pragma unroll
    for (int j = 0; j < FN; j++) acc[i][j] = zero4;

  for (int kt = 0; kt < K; kt += 32) {
#pragma unroll
    for (int c = 0; c < BM * 4; c += 256) {
      int cc = c + tid;
      int row = cc >> 2, kk = (cc & 3) * 8;
      gload16(Az + (long)(tm + row) * lda + kt + kk, &As[cc * 8]);
    }
#pragma unroll
    for (int c = 0; c < BN * 4; c += 256) {
      int cc = c + tid;
      int row = cc >> 2, kk = (cc & 3) * 8;
      gload16(Bz + (long)(tn + row) * ldb + kt + kk, &Bs[cc * 8]);
    }
    __syncthreads();  // drains vmcnt for global_load_lds

    v8s af[FM], bfr[FN];
#pragma unroll
    for (int i = 0; i < FM; i++)
      af[i] = *(const v8s*)&As[(wm + i * 16 + (lane & 15)) * 32 + (lane >> 4) * 8];
#pragma unroll
    for (int j = 0; j < FN; j++)
      bfr[j] = *(const v8s*)&Bs[(wn + j * 16 + (lane & 15)) * 32 + (lane >> 4) * 8];
#pragma unroll
    for (int i = 0; i < FM; i++)
#pragma unroll
      for (int j = 0; j < FN; j++)
        acc[i][j] = __builtin_amdgcn_mfma_f32_16x16x32_bf16(af[i], bfr[j], acc[i][j], 0, 0, 0);
    __syncthreads();
  }

  bool mflag = false;
  if constexpr (MODE == MODE_SCORE) mflag = (*ep.mask_flag != 0);
  bool res_is_f32 = false;
  if constexpr (MODE == MODE_BIAS_RES) res_is_f32 = (ep.res != nullptr);

  // C/D layout (m89/m91-verified): col = lane&15, row = (lane>>4)*4 + r
  if constexpr (MODE == MODE_SCORE) {
    // epilogue + fused column-sum (softmax axis = q/m): atomic per (zl, n)
#pragma unroll
    for (int j = 0; j < FN; j++) {
      int n = tn + wn + j * 16 + (lane & 15);
      int b = (ep.z0 + z) >> 4;
      float csum = 0.f;
#pragma unroll
      for (int i = 0; i < FM; i++) {
        int mbase = tm + wm + i * 16 + ((lane >> 4) << 2);
#pragma unroll
        for (int r = 0; r < 4; r++) {
          int m = mbase + r;
          long idx = (long)m * 1024 + n;
          bool mk = mflag ? (((const int*)ep.mask)[(long)b * 1048576 + idx] != 0)
                          : (ep.mask[(long)b * 1048576 + idx] != 0);
          float sv = mk ? acc[i][j][r] : -1000.0f;  // mask BEFORE scale (ref quirk)
          u16 eb = f2bf(__expf(sv * 0.125f));
          ep.outb[((long)z << 20) + idx] = eb;
          csum += bf2f(eb);  // sum the rounded value PV will actually use
        }
      }
      csum += __shfl_xor(csum, 16);
      csum += __shfl_xor(csum, 32);
      if (lane < 16) atomicAdd(&ep.rcsum[(z << 10) + n], csum);
    }
    return;
  }

#pragma unroll
  for (int i = 0; i < FM; i++) {
    int mbase = tm + wm + i * 16 + ((lane >> 4) << 2);
#pragma unroll
    for (int j = 0; j < FN; j++) {
      int n = tn + wn + j * 16 + (lane & 15);
#pragma unroll
      for (int r = 0; r < 4; r++) {
        float val = acc[i][j][r];
        int m = mbase + r;
        if constexpr (MODE == MODE_QKV) {
          int b = m >> 10, s = m & 1023;
          int w = n >> 10, rr = n & 1023, h = rr >> 6, e = rr & 63;
          long idx = (((long)(b * 16 + h) << 10) + s) * 64 + e;  // [z,s,e]
          u16* dst = (w == 0) ? ep.q : (w == 1) ? ep.k : ep.v;
          dst[idx] = f2bf(val);
        } else if constexpr (MODE == MODE_PV) {
          int zg = ep.z0 + z;
          int b = zg >> 4, h = zg & 15;
          ep.outb[((long)(b * 1024 + m) << 10) + h * 64 + n] = f2bf(val);
        } else if constexpr (MODE == MODE_BIAS_RES) {
          long idx = (long)m * N + n;
          float rres = res_is_f32 ? ep.res[idx] : bf2f(ep.res_bf[idx]);
          ep.outf[idx] = val + ep.bias[n] + rres;
        } else if constexpr (MODE == MODE_BIAS_RELU) {
          float v2 = val + ep.bias[n];
          ep.outb[(long)m * N + n] = f2bf(fmaxf(v2, 0.f));
        }
      }
    }
  }
}

// Transpose V [zl,s,e] -> vT [zl,e,s], scaling column k=s by 1/colsum(s).
// grid (16 s-tiles, CZ), block 256. 64x64 tile via LDS.
__global__ __launch_bounds__(256)
void transpose_scale(const u16* __restrict__ V, const float* __restrict__ rc,
                     u16* __restrict__ vT)
{
  __shared__ u16 t[64 * 66];
  __shared__ float rl[64];
  const int zl = blockIdx.y;
  const int s0 = blockIdx.x * 64;
  const int tid = threadIdx.x;
  const int r = tid >> 2, cg = (tid & 3) << 4;
  const u16* src = V + ((long)zl << 16) + (long)(s0 + r) * 64 + cg;
  v4u16 a0 = *(const v4u16*)(src);
  v4u16 a1 = *(const v4u16*)(src + 4);
  v4u16 a2 = *(const v4u16*)(src + 8);
  v4u16 a3 = *(const v4u16*)(src + 12);
  if (tid < 64) rl[tid] = 1.f / rc[(zl << 10) + s0 + tid];
  u16 tmp[16] = {(u16)a0.x, (u16)a0.y, (u16)a0.z, (u16)a0.w,
                 (u16)a1.x, (u16)a1.y, (u16)a1.z, (u16)a1.w,
                 (u16)a2.x, (u16)a2.y, (u16)a2.z, (u16)a2.w,
                 (u16)a3.x, (u16)a3.y, (u16)a3.z, (u16)a3.w};
#pragma unroll
  for (int i = 0; i < 16; i++) t[(cg + i) * 66 + r] = tmp[i];
  __syncthreads();
  const int e = tid >> 2, sg = (tid & 3) << 4;
  u16* dst = vT + ((long)zl << 16) + (long)e * 1024 + s0 + sg;
  v4u16 o;
#pragma unroll
  for (int q = 0; q < 4; q++) {
#pragma unroll
    for (int w = 0; w < 4; w++) {
      float f = bf2f(t[e * 66 + sg + q * 4 + w]) * rl[sg + q * 4 + w];
      ((u16*)&o)[w] = f2bf(f);
    }
    *(v4u16*)(dst + q * 4) = o;
  }
}

// LayerNorm over 1024 cols; one block per row.
__global__ __launch_bounds__(256)
void ln_kernel(const float* __restrict__ in, const float* __restrict__ gam,
               const float* __restrict__ bet, float* __restrict__ outf,
               u16* __restrict__ outb)
{
  long row = blockIdx.x;
  v4f v = *(const v4f*)(in + (row << 10) + (threadIdx.x << 2));
  float s = v.x + v.y + v.z + v.w;
  float s2 = v.x * v.x + v.y * v.y + v.z * v.z + v.w * v.w;
#pragma unroll
  for (int o = 32; o > 0; o >>= 1) { s += __shfl_down(s, o); s2 += __shfl_down(s2, o); }
  __shared__ float red[8];
  int wv_ = threadIdx.x >> 6, ln = threadIdx.x & 63;
  if (ln == 0) { red[wv_] = s; red[4 + wv_] = s2; }
  __syncthreads();
  float S1 = red[0] + red[1] + red[2] + red[3];
  float S2 = red[4] + red[5] + red[6] + red[7];
  float mu = S1 * (1.f / 1024.f);
  float var = S2 * (1.f / 1024.f) - mu * mu;
  float rstd = rsqrtf(var + 1e-5f);
  v4f g4 = *(const v4f*)(gam + (threadIdx.x << 2));
  v4f b4 = *(const v4f*)(bet + (threadIdx.x << 2));
  v4f o4;
  o4.x = (v.x - mu) * rstd * g4.x + b4.x;
  o4.y = (v.y - mu) * rstd * g4.y + b4.y;
  o4.z = (v.z - mu) * rstd * g4.z + b4.z;
  o4.w = (v.w - mu) * rstd * g4.w + b4.w;
  if (outf) *(v4f*)(outf + (row << 10) + (threadIdx.x << 2)) = o4;
  if (outb) {
    v4u16 u;
    u.x = f2bf(o4.x); u.y = f2bf(o4.y); u.z = f2bf(o4.z); u.w = f2bf(o4.w);
    *(v4u16*)(outb + (row << 10) + (threadIdx.x << 2)) = u;
  }
}

__global__ __launch_bounds__(256)
void cvt_bf16(const float* __restrict__ in, u16* __restrict__ out, int n4)
{
  int i = blockIdx.x * 256 + threadIdx.x;
  if (i >= n4) return;
  v4f v = ((const v4f*)in)[i];
  v4u16 u;
  u.x = f2bf(v.x); u.y = f2bf(v.y); u.z = f2bf(v.z); u.w = f2bf(v.w);
  ((v4u16*)out)[i] = u;
}

// Pack wq/wk/wv [h][d][e] -> B matrix [n = w*1024 + h*64 + e][d] bf16.
__global__ __launch_bounds__(256)
void pack_qkvw(const float* __restrict__ wq, const float* __restrict__ wk,
               const float* __restrict__ wv, u16* __restrict__ out)
{
  int i = blockIdx.x * 256 + threadIdx.x;  // 3*2^20 total
  int w = i >> 20, r = i & 1048575;
  int e = r & 63, d = (r >> 6) & 1023, h = r >> 16;
  const float* src = (w == 0) ? wq : ((w == 1) ? wk : wv);
  float v = src[(((long)h << 10) + d) * 64 + e];
  out[((((long)w << 10) + (h << 6) + e) << 10) + d] = f2bf(v);
}

// Detect whether mask is int32 (bytes at i%4!=0 all zero) or bool bytes.
__global__ void detect_mask_kernel(const unsigned char* __restrict__ m, int* __restrict__ flag)
{
  if (threadIdx.x == 0 && blockIdx.x == 0) {
    int nz = 0;
    for (int i = 0; i < 256; i++)
      if ((i & 3) != 0 && m[i] != 0) nz++;
    *flag = (nz == 0) ? 1 : 0;
  }
}

extern "C" void kernel_launch(void* const* d_in, const int* in_sizes, int n_in,
                              void* d_out, int out_size, void* d_ws, size_t ws_size,
                              hipStream_t stream)
{
  const float* x     = (const float*)d_in[0];
  const unsigned char* mask = (const unsigned char*)d_in[1];
  const float* wq    = (const float*)d_in[2];
  const float* wk    = (const float*)d_in[3];
  const float* wv    = (const float*)d_in[4];
  const float* fc_w  = (const float*)d_in[5];
  const float* fc_b  = (const float*)d_in[6];
  const float* w1    = (const float*)d_in[7];
  const float* b1    = (const float*)d_in[8];
  const float* w2    = (const float*)d_in[9];
  const float* b2    = (const float*)d_in[10];
  const float* ln1_g = (const float*)d_in[11];
  const float* ln1_b = (const float*)d_in[12];
  const float* ln2_g = (const float*)d_in[13];
  const float* ln2_b = (const float*)d_in[14];
  (void)in_sizes; (void)n_in; (void)out_size;

  // ---- workspace map (aliased lifetimes) ----
  const size_t MB = 1ull << 20;
  char* ws = (char*)d_ws;
  int*   mflag = (int*)ws;                  // 4 B
  float* rc    = (float*)(ws + 65536);      // up to 512 KB (CZ*1024 fp32 sums)
  u16*   bqkv  = (u16*)(ws + 1 * MB);       // 6 MB
  u16*   fcb   = (u16*)(ws + 7 * MB);       // 2 MB
  u16*   w1b   = (u16*)(ws + 9 * MB);       // 8 MB
  u16*   w2b   = (u16*)(ws + 17 * MB);      // 8 MB
  u16*   xb    = (u16*)(ws + 25 * MB);      // 16 MB -> x1b alias
  u16*   x1b   = xb;
  u16*   Qb    = (u16*)(ws + 41 * MB);      // 16 MB
  u16*   Kb    = (u16*)(ws + 57 * MB);      // 16 MB
  u16*   Vb    = (u16*)(ws + 73 * MB);      // 16 MB (un-transposed [z,s,e])
  u16*   vT    = (u16*)(ws + 89 * MB);      // 16 MB ([z,e,s], scaled)
  u16*   oc    = (u16*)(ws + 105 * MB);     // 16 MB
  u16*   h1    = (u16*)(ws + 41 * MB);      // 64 MB alias Qb..vT (post-attention)
  float* r1    = (float*)(ws + 121 * MB);   // 32 MB
  u16*   Ech   = (u16*)(ws + 121 * MB);     // 2*CZ MB alias r1 (attention phase)

  // chunk size by available workspace: peak = 121 MB + max(32, 2*CZ) MB
  int CZ;
  if      (ws_size >= 378 * MB) CZ = 128;
  else if (ws_size >= 250 * MB) CZ = 64;
  else if (ws_size >= 186 * MB) CZ = 32;
  else if (ws_size >= 154 * MB) CZ = 16;
  else                          CZ = 8;

  detect_mask_kernel<<<1, 64, 0, stream>>>(mask, mflag);

  cvt_bf16<<<8192, 256, 0, stream>>>(x, xb, 2097152);
  pack_qkvw<<<12288, 256, 0, stream>>>(wq, wk, wv, bqkv);
  cvt_bf16<<<1024, 256, 0, stream>>>(fc_w, fcb, 262144);
  cvt_bf16<<<4096, 256, 0, stream>>>(w1, w1b, 1048576);
  cvt_bf16<<<4096, 256, 0, stream>>>(w2, w2b, 1048576);

  // QKV projections: [8192 x 1024] x [3072 x 1024]^T ; tiles 24x64
  {
    EpArgs ep = {};
    ep.q = Qb; ep.k = Kb; ep.v = Vb;
    gemm_nt<128, 128, 4, 4, MODE_QKV><<<dim3(24 * 64, 1), 256, 0, stream>>>(
        xb, 1024, 0, bqkv, 1024, 0, 1024, 3072, 24, 64, ep);
  }

  // Attention in chunks of CZ (b,h)-slices; E-chunk aliases r1.
  for (int z0 = 0; z0 < 128; z0 += CZ) {
    hipMemsetAsync(rc, 0, (size_t)CZ * 1024 * 4, stream);
    {
      EpArgs ep = {};
      ep.mask = mask; ep.mask_flag = mflag; ep.outb = Ech; ep.rcsum = rc; ep.z0 = z0;
      gemm_nt<128, 128, 4, 4, MODE_SCORE><<<dim3(64, CZ), 256, 0, stream>>>(
          Qb + (long)z0 * 65536, 64, 65536,
          Kb + (long)z0 * 65536, 64, 65536, 64, 1024, 8, 8, ep);
    }
    transpose_scale<<<dim3(16, CZ), 256, 0, stream>>>(
        Vb + (long)z0 * 65536, rc, vT + (long)z0 * 65536);
    {
      EpArgs ep = {};
      ep.outb = oc; ep.z0 = z0;
      gemm_nt<64, 64, 2, 2, MODE_PV><<<dim3(16, CZ), 256, 0, stream>>>(
          Ech, 1024, 1048576,
          vT + (long)z0 * 65536, 1024, 65536, 1024, 64, 1, 16, ep);
    }
  }

  // att = oc @ fc_w^T + fc_b + x -> r1 (fp32) ; tiles 8x64
  {
    EpArgs ep = {};
    ep.bias = fc_b; ep.res = x; ep.outf = r1;
    gemm_nt<128, 128, 4, 4, MODE_BIAS_RES><<<dim3(8 * 64, 1), 256, 0, stream>>>(
        oc, 1024, 0, fcb, 1024, 0, 1024, 1024, 8, 64, ep);
  }
  ln_kernel<<<8192, 256, 0, stream>>>(r1, ln1_g, ln1_b, (float*)nullptr, x1b);
  // h1 = relu(x1 @ w1^T + b1) bf16 ; tiles 32x64
  {
    EpArgs ep = {};
    ep.bias = b1; ep.outb = h1;
    gemm_nt<128, 128, 4, 4, MODE_BIAS_RELU><<<dim3(32 * 64, 1), 256, 0, stream>>>(
        x1b, 1024, 0, w1b, 1024, 0, 1024, 4096, 32, 64, ep);
  }
  // r2 = h1 @ w2^T + b2 + x1(bf16) -> r1 (fp32) ; tiles 8x64
  {
    EpArgs ep = {};
    ep.bias = b2; ep.res_bf = x1b; ep.outf = r1;
    gemm_nt<128, 128, 4, 4, MODE_BIAS_RES><<<dim3(8 * 64, 1), 256, 0, stream>>>(
        h1, 4096, 0, w2b, 4096, 0, 4096, 1024, 8, 64, ep);
  }
  ln_kernel<<<8192, 256, 0, stream>>>(r1, ln2_g, ln2_b, (float*)d_out, (u16*)nullptr);
}

// Round 4
// 771.360 us; speedup vs baseline: 1.7455x; 1.2942x over previous
//
#include <hip/hip_runtime.h>
#include <stdint.h>

#define DEV static __device__ __forceinline__

typedef unsigned short u16;
typedef __attribute__((ext_vector_type(8))) short v8s;    // 8 x bf16 MFMA operand
typedef __attribute__((ext_vector_type(4))) float v4f;
typedef __attribute__((ext_vector_type(4))) unsigned short v4u16;

DEV u16 f2bf(float f) {
  union { float f; unsigned u; } c; c.f = f;
  unsigned r = c.u + 0x7FFFu + ((c.u >> 16) & 1u);
  return (u16)(r >> 16);
}
DEV float bf2f(u16 h) {
  union { unsigned u; float f; } c; c.u = ((unsigned)h) << 16;
  return c.f;
}

// async global->LDS, 16B per lane; LDS dest = wave-uniform base + lane*16.
DEV void gload16(const u16* g, u16* l) {
  __builtin_amdgcn_global_load_lds(
      (const __attribute__((address_space(1))) unsigned int*)g,
      (__attribute__((address_space(3))) unsigned int*)l, 16, 0, 0);
}

enum { MODE_QKV = 0, MODE_BIAS_RES = 3, MODE_BIAS_RELU = 4 };

struct EpArgs {
  const float* bias;          // BIAS_*
  const float* res;           // BIAS_RES fp32 residual (or null)
  const u16* res_bf;          // BIAS_RES bf16 residual (used if res==null)
  float* outf;                // BIAS_RES
  u16* outb;                  // BIAS_RELU
  u16* q; u16* k; u16* v;     // QKV scatter (all [z,s,e])
};

// NT GEMM: C[m][n] = sum_k A[m][k]*B[n][k]. BK=32, 256 thr = 4 waves (2x2).
// Tiles flattened into grid.x, XCD-aware swizzle (nby multiple of 8).
template <int BM, int BN, int FM, int FN, int MODE>
__global__ __launch_bounds__(256, 2)
void gemm_nt(const u16* __restrict__ A, int lda,
             const u16* __restrict__ B, int ldb,
             int K, int N, int nbx, int nby, EpArgs ep)
{
  __shared__ u16 As[BM * 32];
  __shared__ u16 Bs[BN * 32];

  const int tid  = threadIdx.x;
  const int lane = tid & 63;
  const int wave = tid >> 6;
  const int wm = (wave >> 1) * (FM * 16);
  const int wn = (wave & 1) * (FN * 16);

  const int id = blockIdx.x;
  const int nby8 = nby >> 3;
  const int c8 = id & 7, jj = id >> 3;
  const int tm = ((jj % nby8) * 8 + c8) * BM;
  const int tn = (jj / nby8) * BN;

  v4f acc[FM][FN];
  const v4f zero4 = {0.f, 0.f, 0.f, 0.f};
#pragma unroll
  for (int i = 0; i < FM; i++)
#pragma unroll
    for (int j = 0; j < FN; j++) acc[i][j] = zero4;

  for (int kt = 0; kt < K; kt += 32) {
#pragma unroll
    for (int c = 0; c < BM * 4; c += 256) {
      int cc = c + tid;
      int row = cc >> 2, kk = (cc & 3) * 8;
      gload16(A + (long)(tm + row) * lda + kt + kk, &As[cc * 8]);
    }
#pragma unroll
    for (int c = 0; c < BN * 4; c += 256) {
      int cc = c + tid;
      int row = cc >> 2, kk = (cc & 3) * 8;
      gload16(B + (long)(tn + row) * ldb + kt + kk, &Bs[cc * 8]);
    }
    __syncthreads();

    v8s af[FM], bfr[FN];
#pragma unroll
    for (int i = 0; i < FM; i++)
      af[i] = *(const v8s*)&As[(wm + i * 16 + (lane & 15)) * 32 + (lane >> 4) * 8];
#pragma unroll
    for (int j = 0; j < FN; j++)
      bfr[j] = *(const v8s*)&Bs[(wn + j * 16 + (lane & 15)) * 32 + (lane >> 4) * 8];
#pragma unroll
    for (int i = 0; i < FM; i++)
#pragma unroll
      for (int j = 0; j < FN; j++)
        acc[i][j] = __builtin_amdgcn_mfma_f32_16x16x32_bf16(af[i], bfr[j], acc[i][j], 0, 0, 0);
    __syncthreads();
  }

  bool res_is_f32 = false;
  if constexpr (MODE == MODE_BIAS_RES) res_is_f32 = (ep.res != nullptr);

  // C/D layout: col = lane&15, row = (lane>>4)*4 + r
#pragma unroll
  for (int i = 0; i < FM; i++) {
    int mbase = tm + wm + i * 16 + ((lane >> 4) << 2);
#pragma unroll
    for (int j = 0; j < FN; j++) {
      int n = tn + wn + j * 16 + (lane & 15);
#pragma unroll
      for (int r = 0; r < 4; r++) {
        float val = acc[i][j][r];
        int m = mbase + r;
        if constexpr (MODE == MODE_QKV) {
          int b = m >> 10, s = m & 1023;
          int w = n >> 10, rr = n & 1023, h = rr >> 6, e = rr & 63;
          long idx = (((long)(b * 16 + h) << 10) + s) * 64 + e;  // [z,s,e]
          u16* dst = (w == 0) ? ep.q : (w == 1) ? ep.k : ep.v;
          dst[idx] = f2bf(val);
        } else if constexpr (MODE == MODE_BIAS_RES) {
          long idx = (long)m * N + n;
          float rres = res_is_f32 ? ep.res[idx] : bf2f(ep.res_bf[idx]);
          ep.outf[idx] = val + ep.bias[n] + rres;
        } else if constexpr (MODE == MODE_BIAS_RELU) {
          float v2 = val + ep.bias[n];
          ep.outb[(long)m * N + n] = f2bf(fmaxf(v2, 0.f));
        }
      }
    }
  }
}

// ---- fused attention (no E materialization) ----
// Pass 1: per (z, q-tile 128): S = Q K^T, E = exp(masked/8) bf16-rounded,
// column partial sums -> atomicAdd rc[z][k]. grid (8, 128).
__global__ __launch_bounds__(256, 2)
void attn_colsum(const u16* __restrict__ Q, const u16* __restrict__ Kb,
                 const unsigned char* __restrict__ Mb, float* __restrict__ rc)
{
  __shared__ u16 Qs[2 * 128 * 32];  // 16 KB [slab][row][32]
  __shared__ u16 Ks[2 * 128 * 32];  // 16 KB
  const int tid = threadIdx.x, lane = tid & 63, wave = tid >> 6;
  const int wm = (wave >> 1) * 64, wn = (wave & 1) * 64;
  const int z = blockIdx.y, q0 = blockIdx.x * 128, b = z >> 4;
  const u16* Qz = Q + ((long)z << 16);
  const u16* Kz = Kb + ((long)z << 16);
  const unsigned char* Mz = Mb + ((long)b << 20);

  // stage Q once: 1024 chunks of 8 u16
#pragma unroll
  for (int c = 0; c < 4; c++) {
    int cc = c * 256 + tid;
    int s = cc >> 9, rem = cc & 511, row = rem >> 2, k0 = (rem & 3) * 8;
    gload16(Qz + (long)(q0 + row) * 64 + s * 32 + k0, &Qs[cc * 8]);
  }

  for (int nt = 0; nt < 8; nt++) {
    int n0 = nt * 128;
#pragma unroll
    for (int c = 0; c < 4; c++) {
      int cc = c * 256 + tid;
      int s = cc >> 9, rem = cc & 511, row = rem >> 2, k0 = (rem & 3) * 8;
      gload16(Kz + (long)(n0 + row) * 64 + s * 32 + k0, &Ks[cc * 8]);
    }
    __syncthreads();

    v4f sacc[4][4];
    const v4f zero4 = {0.f, 0.f, 0.f, 0.f};
#pragma unroll
    for (int i = 0; i < 4; i++)
#pragma unroll
      for (int j = 0; j < 4; j++) sacc[i][j] = zero4;
#pragma unroll
    for (int s = 0; s < 2; s++) {
      v8s af[4], bf[4];
#pragma unroll
      for (int i = 0; i < 4; i++)
        af[i] = *(const v8s*)&Qs[s * 4096 + (wm + i * 16 + (lane & 15)) * 32 + (lane >> 4) * 8];
#pragma unroll
      for (int j = 0; j < 4; j++)
        bf[j] = *(const v8s*)&Ks[s * 4096 + (wn + j * 16 + (lane & 15)) * 32 + (lane >> 4) * 8];
#pragma unroll
      for (int i = 0; i < 4; i++)
#pragma unroll
        for (int j = 0; j < 4; j++)
          sacc[i][j] = __builtin_amdgcn_mfma_f32_16x16x32_bf16(af[i], bf[j], sacc[i][j], 0, 0, 0);
    }

#pragma unroll
    for (int j = 0; j < 4; j++) {
      int n = n0 + wn + j * 16 + (lane & 15);
      float csum = 0.f;
#pragma unroll
      for (int i = 0; i < 4; i++) {
        int mbase = q0 + wm + i * 16 + ((lane >> 4) << 2);
#pragma unroll
        for (int r = 0; r < 4; r++) {
          int m = mbase + r;
          bool mk = Mz[(long)m * 1024 + n] != 0;
          float sv = mk ? sacc[i][j][r] : -1000.0f;  // mask BEFORE scale (ref quirk)
          csum += bf2f(f2bf(__expf(sv * 0.125f)));   // exact value pass 2 will use
        }
      }
      csum += __shfl_xor(csum, 16);
      csum += __shfl_xor(csum, 32);
      if (lane < 16) atomicAdd(&rc[(z << 10) + n], csum);
    }
    __syncthreads();  // before next K-tile restage
  }
}

// Pass 2: per (z, q-tile 128): recompute S, E -> P(LDS), O += P * V'. grid (8, 128).
__global__ __launch_bounds__(256, 2)
void attn_pv(const u16* __restrict__ Q, const u16* __restrict__ Kb,
             const u16* __restrict__ vT, const unsigned char* __restrict__ Mb,
             u16* __restrict__ oc)
{
  __shared__ u16 Ks[2 * 128 * 32];  // 16 KB (also used to stage Q initially)
  __shared__ u16 Vs[4 * 64 * 32];   // 16 KB [slab][v][32]
  __shared__ u16 Ps[4 * 128 * 32];  // 32 KB [slab][q][32]
  const int tid = threadIdx.x, lane = tid & 63, wave = tid >> 6;
  const int wm = (wave >> 1) * 64;
  const int wn = (wave & 1) * 64;    // QK phase: key split
  const int wnv = (wave & 1) * 32;   // PV phase: v split
  const int z = blockIdx.y, q0 = blockIdx.x * 128, b = z >> 4, h = z & 15;
  const u16* Qz = Q + ((long)z << 16);
  const u16* Kz = Kb + ((long)z << 16);
  const u16* Vz = vT + ((long)z << 16);
  const unsigned char* Mz = Mb + ((long)b << 20);

  // stage Q via Ks buffer, move to registers
#pragma unroll
  for (int c = 0; c < 4; c++) {
    int cc = c * 256 + tid;
    int s = cc >> 9, rem = cc & 511, row = rem >> 2, k0 = (rem & 3) * 8;
    gload16(Qz + (long)(q0 + row) * 64 + s * 32 + k0, &Ks[cc * 8]);
  }
  __syncthreads();
  v8s qf[4][2];
#pragma unroll
  for (int i = 0; i < 4; i++)
#pragma unroll
    for (int s = 0; s < 2; s++)
      qf[i][s] = *(const v8s*)&Ks[s * 4096 + (wm + i * 16 + (lane & 15)) * 32 + (lane >> 4) * 8];
  __syncthreads();  // done reading before restage

  v4f oacc[4][2];
  const v4f zero4 = {0.f, 0.f, 0.f, 0.f};
#pragma unroll
  for (int i = 0; i < 4; i++)
#pragma unroll
    for (int j = 0; j < 2; j++) oacc[i][j] = zero4;

  for (int nt = 0; nt < 8; nt++) {
    int n0 = nt * 128;
    // stage K-tile [128 keys][64] and V'-tile [64 v][128 keys]
#pragma unroll
    for (int c = 0; c < 4; c++) {
      int cc = c * 256 + tid;
      int s = cc >> 9, rem = cc & 511, row = rem >> 2, k0 = (rem & 3) * 8;
      gload16(Kz + (long)(n0 + row) * 64 + s * 32 + k0, &Ks[cc * 8]);
    }
#pragma unroll
    for (int c = 0; c < 4; c++) {
      int cc = c * 256 + tid;
      int s = cc >> 8, rem = cc & 255, v = rem >> 2, k0 = (rem & 3) * 8;
      gload16(Vz + (long)v * 1024 + n0 + s * 32 + k0, &Vs[cc * 8]);
    }
    __syncthreads();

    // S = Q K^T for this key tile
    v4f sacc[4][4];
#pragma unroll
    for (int i = 0; i < 4; i++)
#pragma unroll
      for (int j = 0; j < 4; j++) sacc[i][j] = zero4;
#pragma unroll
    for (int s = 0; s < 2; s++) {
      v8s bf[4];
#pragma unroll
      for (int j = 0; j < 4; j++)
        bf[j] = *(const v8s*)&Ks[s * 4096 + (wn + j * 16 + (lane & 15)) * 32 + (lane >> 4) * 8];
#pragma unroll
      for (int i = 0; i < 4; i++)
#pragma unroll
        for (int j = 0; j < 4; j++)
          sacc[i][j] = __builtin_amdgcn_mfma_f32_16x16x32_bf16(qf[i][s], bf[j], sacc[i][j], 0, 0, 0);
    }

    // E = exp(masked/8) -> P tile in LDS (A-operand layout [slab][q][32])
#pragma unroll
    for (int i = 0; i < 4; i++) {
      int mlb = wm + i * 16 + ((lane >> 4) << 2);
#pragma unroll
      for (int j = 0; j < 4; j++) {
        int col = wn + j * 16 + (lane & 15);
        int gn = n0 + col;
#pragma unroll
        for (int r = 0; r < 4; r++) {
          int ml = mlb + r;
          bool mk = Mz[(long)(q0 + ml) * 1024 + gn] != 0;
          float sv = mk ? sacc[i][j][r] : -1000.0f;
          Ps[(col >> 5) * 4096 + ml * 32 + (col & 31)] = f2bf(__expf(sv * 0.125f));
        }
      }
    }
    __syncthreads();

    // O += P * V'
#pragma unroll
    for (int s = 0; s < 4; s++) {
      v8s vf[2];
#pragma unroll
      for (int j = 0; j < 2; j++)
        vf[j] = *(const v8s*)&Vs[s * 2048 + (wnv + j * 16 + (lane & 15)) * 32 + (lane >> 4) * 8];
#pragma unroll
      for (int i = 0; i < 4; i++) {
        v8s pf = *(const v8s*)&Ps[s * 4096 + (wm + i * 16 + (lane & 15)) * 32 + (lane >> 4) * 8];
#pragma unroll
        for (int j = 0; j < 2; j++)
          oacc[i][j] = __builtin_amdgcn_mfma_f32_16x16x32_bf16(pf, vf[j], oacc[i][j], 0, 0, 0);
      }
    }
    __syncthreads();  // before next restage
  }

  // write O: oc[(b*1024 + q) * 1024 + h*64 + v]
#pragma unroll
  for (int i = 0; i < 4; i++) {
    int mbase = q0 + wm + i * 16 + ((lane >> 4) << 2);
#pragma unroll
    for (int j = 0; j < 2; j++) {
      int n = wnv + j * 16 + (lane & 15);
#pragma unroll
      for (int r = 0; r < 4; r++) {
        int m = mbase + r;
        oc[((long)(b * 1024 + m) << 10) + h * 64 + n] = f2bf(oacc[i][j][r]);
      }
    }
  }
}

// Transpose V [z,s,e] -> vT [z,e,s], scaling column s by 1/colsum(s). grid (16, 128).
__global__ __launch_bounds__(256)
void transpose_scale(const u16* __restrict__ V, const float* __restrict__ rc,
                     u16* __restrict__ vT)
{
  __shared__ u16 t[64 * 66];
  __shared__ float rl[64];
  const int zl = blockIdx.y;
  const int s0 = blockIdx.x * 64;
  const int tid = threadIdx.x;
  const int r = tid >> 2, cg = (tid & 3) << 4;
  const u16* src = V + ((long)zl << 16) + (long)(s0 + r) * 64 + cg;
  v4u16 a0 = *(const v4u16*)(src);
  v4u16 a1 = *(const v4u16*)(src + 4);
  v4u16 a2 = *(const v4u16*)(src + 8);
  v4u16 a3 = *(const v4u16*)(src + 12);
  if (tid < 64) rl[tid] = 1.f / rc[(zl << 10) + s0 + tid];
  u16 tmp[16] = {(u16)a0.x, (u16)a0.y, (u16)a0.z, (u16)a0.w,
                 (u16)a1.x, (u16)a1.y, (u16)a1.z, (u16)a1.w,
                 (u16)a2.x, (u16)a2.y, (u16)a2.z, (u16)a2.w,
                 (u16)a3.x, (u16)a3.y, (u16)a3.z, (u16)a3.w};
#pragma unroll
  for (int i = 0; i < 16; i++) t[(cg + i) * 66 + r] = tmp[i];
  __syncthreads();
  const int e = tid >> 2, sg = (tid & 3) << 4;
  u16* dst = vT + ((long)zl << 16) + (long)e * 1024 + s0 + sg;
  v4u16 o;
#pragma unroll
  for (int q = 0; q < 4; q++) {
#pragma unroll
    for (int w = 0; w < 4; w++) {
      float f = bf2f(t[e * 66 + sg + q * 4 + w]) * rl[sg + q * 4 + w];
      ((u16*)&o)[w] = f2bf(f);
    }
    *(v4u16*)(dst + q * 4) = o;
  }
}

// LayerNorm over 1024 cols; one block per row.
__global__ __launch_bounds__(256)
void ln_kernel(const float* __restrict__ in, const float* __restrict__ gam,
               const float* __restrict__ bet, float* __restrict__ outf,
               u16* __restrict__ outb)
{
  long row = blockIdx.x;
  v4f v = *(const v4f*)(in + (row << 10) + (threadIdx.x << 2));
  float s = v.x + v.y + v.z + v.w;
  float s2 = v.x * v.x + v.y * v.y + v.z * v.z + v.w * v.w;
#pragma unroll
  for (int o = 32; o > 0; o >>= 1) { s += __shfl_down(s, o); s2 += __shfl_down(s2, o); }
  __shared__ float red[8];
  int wv_ = threadIdx.x >> 6, ln = threadIdx.x & 63;
  if (ln == 0) { red[wv_] = s; red[4 + wv_] = s2; }
  __syncthreads();
  float S1 = red[0] + red[1] + red[2] + red[3];
  float S2 = red[4] + red[5] + red[6] + red[7];
  float mu = S1 * (1.f / 1024.f);
  float var = S2 * (1.f / 1024.f) - mu * mu;
  float rstd = rsqrtf(var + 1e-5f);
  v4f g4 = *(const v4f*)(gam + (threadIdx.x << 2));
  v4f b4 = *(const v4f*)(bet + (threadIdx.x << 2));
  v4f o4;
  o4.x = (v.x - mu) * rstd * g4.x + b4.x;
  o4.y = (v.y - mu) * rstd * g4.y + b4.y;
  o4.z = (v.z - mu) * rstd * g4.z + b4.z;
  o4.w = (v.w - mu) * rstd * g4.w + b4.w;
  if (outf) *(v4f*)(outf + (row << 10) + (threadIdx.x << 2)) = o4;
  if (outb) {
    v4u16 u;
    u.x = f2bf(o4.x); u.y = f2bf(o4.y); u.z = f2bf(o4.z); u.w = f2bf(o4.w);
    *(v4u16*)(outb + (row << 10) + (threadIdx.x << 2)) = u;
  }
}

__global__ __launch_bounds__(256)
void cvt_bf16(const float* __restrict__ in, u16* __restrict__ out, int n4)
{
  int i = blockIdx.x * 256 + threadIdx.x;
  if (i >= n4) return;
  v4f v = ((const v4f*)in)[i];
  v4u16 u;
  u.x = f2bf(v.x); u.y = f2bf(v.y); u.z = f2bf(v.z); u.w = f2bf(v.w);
  ((v4u16*)out)[i] = u;
}

// Pack wq/wk/wv [h][d][e] -> B matrix [n = w*1024 + h*64 + e][d] bf16.
__global__ __launch_bounds__(256)
void pack_qkvw(const float* __restrict__ wq, const float* __restrict__ wk,
               const float* __restrict__ wv, u16* __restrict__ out)
{
  int i = blockIdx.x * 256 + threadIdx.x;  // 3*2^20 total
  int w = i >> 20, r = i & 1048575;
  int e = r & 63, d = (r >> 6) & 1023, h = r >> 16;
  const float* src = (w == 0) ? wq : ((w == 1) ? wk : wv);
  float v = src[(((long)h << 10) + d) * 64 + e];
  out[((((long)w << 10) + (h << 6) + e) << 10) + d] = f2bf(v);
}

// Detect whether mask is int32 (bytes at i%4!=0 all zero) or bool bytes.
__global__ void detect_mask_kernel(const unsigned char* __restrict__ m, int* __restrict__ flag)
{
  if (threadIdx.x == 0 && blockIdx.x == 0) {
    int nz = 0;
    for (int i = 0; i < 256; i++)
      if ((i & 3) != 0 && m[i] != 0) nz++;
    *flag = (nz == 0) ? 1 : 0;
  }
}

// Canonicalize mask (byte or int32) into u8 {0,1}. 4 outputs/thread, 8M total.
__global__ __launch_bounds__(256)
void canon_mask(const unsigned char* __restrict__ m, const int* __restrict__ flag,
                unsigned char* __restrict__ out)
{
  int i = blockIdx.x * 256 + threadIdx.x;  // handles bytes [4i, 4i+4)
  uchar4 o;
  if (*flag) {
    const int* mi = (const int*)m;
    o.x = mi[i * 4 + 0] != 0; o.y = mi[i * 4 + 1] != 0;
    o.z = mi[i * 4 + 2] != 0; o.w = mi[i * 4 + 3] != 0;
  } else {
    o = ((const uchar4*)m)[i];
  }
  ((uchar4*)out)[i] = o;
}

extern "C" void kernel_launch(void* const* d_in, const int* in_sizes, int n_in,
                              void* d_out, int out_size, void* d_ws, size_t ws_size,
                              hipStream_t stream)
{
  const float* x     = (const float*)d_in[0];
  const unsigned char* mask = (const unsigned char*)d_in[1];
  const float* wq    = (const float*)d_in[2];
  const float* wk    = (const float*)d_in[3];
  const float* wv    = (const float*)d_in[4];
  const float* fc_w  = (const float*)d_in[5];
  const float* fc_b  = (const float*)d_in[6];
  const float* w1    = (const float*)d_in[7];
  const float* b1    = (const float*)d_in[8];
  const float* w2    = (const float*)d_in[9];
  const float* b2    = (const float*)d_in[10];
  const float* ln1_g = (const float*)d_in[11];
  const float* ln1_b = (const float*)d_in[12];
  const float* ln2_g = (const float*)d_in[13];
  const float* ln2_b = (const float*)d_in[14];
  (void)in_sizes; (void)n_in; (void)out_size; (void)ws_size;

  // ---- workspace map (aliased lifetimes), peak 137 MB ----
  const size_t MB = 1ull << 20;
  char* ws = (char*)d_ws;
  int*   mflag = (int*)ws;                  // 4 B
  float* rc    = (float*)(ws + 65536);      // 512 KB (128*1024 fp32 colsums)
  u16*   bqkv  = (u16*)(ws + 1 * MB);       // 6 MB
  u16*   fcb   = (u16*)(ws + 7 * MB);       // 2 MB
  u16*   w1b   = (u16*)(ws + 9 * MB);       // 8 MB
  u16*   w2b   = (u16*)(ws + 17 * MB);      // 8 MB
  u16*   xb    = (u16*)(ws + 25 * MB);      // 16 MB -> x1b alias
  u16*   x1b   = xb;
  u16*   Qb    = (u16*)(ws + 41 * MB);      // 16 MB
  u16*   Kb    = (u16*)(ws + 57 * MB);      // 16 MB
  u16*   Vb    = (u16*)(ws + 73 * MB);      // 16 MB (un-transposed [z,s,e])
  u16*   vT    = (u16*)(ws + 89 * MB);      // 16 MB ([z,e,s], scaled)
  u16*   oc    = (u16*)(ws + 105 * MB);     // 16 MB
  u16*   h1    = (u16*)(ws + 41 * MB);      // 64 MB alias Qb..vT (post-attention)
  float* r1    = (float*)(ws + 121 * MB);   // 32 MB (post-attention)
  unsigned char* Mb = (unsigned char*)(ws + 121 * MB);  // 8 MB alias r1 (attn phase)

  detect_mask_kernel<<<1, 64, 0, stream>>>(mask, mflag);
  canon_mask<<<8192, 256, 0, stream>>>(mask, mflag, Mb);

  cvt_bf16<<<8192, 256, 0, stream>>>(x, xb, 2097152);
  pack_qkvw<<<12288, 256, 0, stream>>>(wq, wk, wv, bqkv);
  cvt_bf16<<<1024, 256, 0, stream>>>(fc_w, fcb, 262144);
  cvt_bf16<<<4096, 256, 0, stream>>>(w1, w1b, 1048576);
  cvt_bf16<<<4096, 256, 0, stream>>>(w2, w2b, 1048576);

  // QKV projections: [8192 x 1024] x [3072 x 1024]^T ; tiles 24x64
  {
    EpArgs ep = {};
    ep.q = Qb; ep.k = Kb; ep.v = Vb;
    gemm_nt<128, 128, 4, 4, MODE_QKV><<<dim3(24 * 64, 1), 256, 0, stream>>>(
        xb, 1024, bqkv, 1024, 1024, 3072, 24, 64, ep);
  }

  // Fused attention: colsum pass -> scale V -> PV pass (no E in HBM)
  hipMemsetAsync(rc, 0, 128 * 1024 * 4, stream);
  attn_colsum<<<dim3(8, 128), 256, 0, stream>>>(Qb, Kb, Mb, rc);
  transpose_scale<<<dim3(16, 128), 256, 0, stream>>>(Vb, rc, vT);
  attn_pv<<<dim3(8, 128), 256, 0, stream>>>(Qb, Kb, vT, Mb, oc);

  // att = oc @ fc_w^T + fc_b + x -> r1 (fp32) ; tiles 8x64
  {
    EpArgs ep = {};
    ep.bias = fc_b; ep.res = x; ep.outf = r1;
    gemm_nt<128, 128, 4, 4, MODE_BIAS_RES><<<dim3(8 * 64, 1), 256, 0, stream>>>(
        oc, 1024, fcb, 1024, 1024, 1024, 8, 64, ep);
  }
  ln_kernel<<<8192, 256, 0, stream>>>(r1, ln1_g, ln1_b, (float*)nullptr, x1b);
  // h1 = relu(x1 @ w1^T + b1) bf16 ; tiles 32x64
  {
    EpArgs ep = {};
    ep.bias = b1; ep.outb = h1;
    gemm_nt<128, 128, 4, 4, MODE_BIAS_RELU><<<dim3(32 * 64, 1), 256, 0, stream>>>(
        x1b, 1024, w1b, 1024, 1024, 4096, 32, 64, ep);
  }
  // r2 = h1 @ w2^T + b2 + x1(bf16) -> r1 (fp32) ; tiles 8x64
  {
    EpArgs ep = {};
    ep.bias = b2; ep.res_bf = x1b; ep.outf = r1;
    gemm_nt<128, 128, 4, 4, MODE_BIAS_RES><<<dim3(8 * 64, 1), 256, 0, stream>>>(
        h1, 4096, w2b, 4096, 4096, 1024, 8, 64, ep);
  }
  ln_kernel<<<8192, 256, 0, stream>>>(r1, ln2_g, ln2_b, (float*)d_out, (u16*)nullptr);
}

// Round 5
// 713.567 us; speedup vs baseline: 1.8868x; 1.0810x over previous
//
#include <hip/hip_runtime.h>
#include <stdint.h>

#define DEV static __device__ __forceinline__

typedef unsigned short u16;
typedef __attribute__((ext_vector_type(8))) short v8s;    // 8 x bf16 MFMA operand
typedef __attribute__((ext_vector_type(4))) float v4f;
typedef __attribute__((ext_vector_type(4))) unsigned short v4u16;

DEV u16 f2bf(float f) {
  union { float f; unsigned u; } c; c.f = f;
  unsigned r = c.u + 0x7FFFu + ((c.u >> 16) & 1u);
  return (u16)(r >> 16);
}
DEV float bf2f(u16 h) {
  union { unsigned u; float f; } c; c.u = ((unsigned)h) << 16;
  return c.f;
}

// async global->LDS, 16B per lane; LDS dest = wave-uniform base + lane*16.
DEV void gload16(const u16* g, u16* l) {
  __builtin_amdgcn_global_load_lds(
      (const __attribute__((address_space(1))) unsigned int*)g,
      (__attribute__((address_space(3))) unsigned int*)l, 16, 0, 0);
}

enum { MODE_QKV = 0, MODE_PV = 2, MODE_BIAS_RES = 3, MODE_BIAS_RELU = 4 };

struct EpArgs {
  const float* bias;          // BIAS_*
  const float* res;           // BIAS_RES fp32 residual (or null)
  const u16* res_bf;          // BIAS_RES bf16 residual (used if res==null)
  float* outf;                // BIAS_RES
  u16* outb;                  // PV/BIAS_RELU
  u16* q; u16* k; u16* v;     // QKV scatter (all [z,s,e])
  int z0;                     // chunk base z for PV
};

// NT GEMM: C[m][n] = sum_k A[m][k]*B[n][k]. BK=32, 256 thr = 4 waves (2x2).
// Tiles flattened into grid.x, XCD-aware swizzle (nby multiple of 8). z = blockIdx.y.
template <int BM, int BN, int FM, int FN, int MODE>
__global__ __launch_bounds__(256, 2)
void gemm_nt(const u16* __restrict__ A, int lda, long sA,
             const u16* __restrict__ B, int ldb, long sB,
             int K, int N, int nbx, int nby, EpArgs ep)
{
  __shared__ u16 As[BM * 32];
  __shared__ u16 Bs[BN * 32];

  const int tid  = threadIdx.x;
  const int lane = tid & 63;
  const int wave = tid >> 6;
  const int wm = (wave >> 1) * (FM * 16);
  const int wn = (wave & 1) * (FN * 16);

  const int id = blockIdx.x;
  const int nby8 = nby >> 3;
  const int c8 = id & 7, jj = id >> 3;
  const int tm = ((jj % nby8) * 8 + c8) * BM;
  const int tn = (jj / nby8) * BN;
  const int z  = blockIdx.y;

  const u16* Az = A + (long)z * sA;
  const u16* Bz = B + (long)z * sB;

  v4f acc[FM][FN];
  const v4f zero4 = {0.f, 0.f, 0.f, 0.f};
#pragma unroll
  for (int i = 0; i < FM; i++)
#pragma unroll
    for (int j = 0; j < FN; j++) acc[i][j] = zero4;

  for (int kt = 0; kt < K; kt += 32) {
#pragma unroll
    for (int c = 0; c < BM * 4; c += 256) {
      int cc = c + tid;
      int row = cc >> 2, kk = (cc & 3) * 8;
      gload16(Az + (long)(tm + row) * lda + kt + kk, &As[cc * 8]);
    }
#pragma unroll
    for (int c = 0; c < BN * 4; c += 256) {
      int cc = c + tid;
      int row = cc >> 2, kk = (cc & 3) * 8;
      gload16(Bz + (long)(tn + row) * ldb + kt + kk, &Bs[cc * 8]);
    }
    __syncthreads();

    v8s af[FM], bfr[FN];
#pragma unroll
    for (int i = 0; i < FM; i++)
      af[i] = *(const v8s*)&As[(wm + i * 16 + (lane & 15)) * 32 + (lane >> 4) * 8];
#pragma unroll
    for (int j = 0; j < FN; j++)
      bfr[j] = *(const v8s*)&Bs[(wn + j * 16 + (lane & 15)) * 32 + (lane >> 4) * 8];
#pragma unroll
    for (int i = 0; i < FM; i++)
#pragma unroll
      for (int j = 0; j < FN; j++)
        acc[i][j] = __builtin_amdgcn_mfma_f32_16x16x32_bf16(af[i], bfr[j], acc[i][j], 0, 0, 0);
    __syncthreads();
  }

  bool res_is_f32 = false;
  if constexpr (MODE == MODE_BIAS_RES) res_is_f32 = (ep.res != nullptr);

  // C/D layout: col = lane&15, row = (lane>>4)*4 + r
#pragma unroll
  for (int i = 0; i < FM; i++) {
    int mbase = tm + wm + i * 16 + ((lane >> 4) << 2);
#pragma unroll
    for (int j = 0; j < FN; j++) {
      int n = tn + wn + j * 16 + (lane & 15);
#pragma unroll
      for (int r = 0; r < 4; r++) {
        float val = acc[i][j][r];
        int m = mbase + r;
        if constexpr (MODE == MODE_QKV) {
          int b = m >> 10, s = m & 1023;
          int w = n >> 10, rr = n & 1023, h = rr >> 6, e = rr & 63;
          long idx = (((long)(b * 16 + h) << 10) + s) * 64 + e;  // [z,s,e]
          u16* dst = (w == 0) ? ep.q : (w == 1) ? ep.k : ep.v;
          dst[idx] = f2bf(val);
        } else if constexpr (MODE == MODE_PV) {
          int zg = ep.z0 + z;
          int b = zg >> 4, h = zg & 15;
          ep.outb[((long)(b * 1024 + m) << 10) + h * 64 + n] = f2bf(val);
        } else if constexpr (MODE == MODE_BIAS_RES) {
          long idx = (long)m * N + n;
          float rres = res_is_f32 ? ep.res[idx] : bf2f(ep.res_bf[idx]);
          ep.outf[idx] = val + ep.bias[n] + rres;
        } else if constexpr (MODE == MODE_BIAS_RELU) {
          float v2 = val + ep.bias[n];
          ep.outb[(long)m * N + n] = f2bf(fmaxf(v2, 0.f));
        }
      }
    }
  }
}

// ---- attention pass 1: S = Q K^T, E = exp(masked/8) bf16, colsum atomics,
// coalesced E store. One 128x128 tile per block; grid (8 ktile, 8 qtile, CZ).
// Mask from bit-packed Mpk, staged to LDS (2 KB/tile).
__global__ __launch_bounds__(256, 4)
void attn_score(const u16* __restrict__ Q, const u16* __restrict__ Kb,
                const unsigned char* __restrict__ Mpk, float* __restrict__ rc,
                u16* __restrict__ E, int z0)
{
  __shared__ u16 sh[17408];           // 34816 B: Q/K staging (32 KB), reused as P (stride 136)
  __shared__ unsigned char Ms[2048];  // mask bits for this 128x128 tile
  const int tid = threadIdx.x, lane = tid & 63, wave = tid >> 6;
  const int wm = (wave >> 1) * 64, wn = (wave & 1) * 64;
  const int zl = blockIdx.z, q0 = blockIdx.y * 128, n0 = blockIdx.x * 128;
  const int b = (z0 + zl) >> 4;
  const u16* Qz = Q + ((long)zl << 16);
  const u16* Kz = Kb + ((long)zl << 16);
  u16* Qs = sh;           // [2 slabs][128][32]
  u16* Ks = sh + 8192;
  u16* Ps = sh;           // reuse after MFMA, row stride 136 u16

#pragma unroll
  for (int c = 0; c < 4; c++) {
    int cc = c * 256 + tid;
    int s = cc >> 9, rem = cc & 511, row = rem >> 2, k0 = (rem & 3) * 8;
    gload16(Qz + (long)(q0 + row) * 64 + s * 32 + k0, &Qs[cc * 8]);
  }
#pragma unroll
  for (int c = 0; c < 4; c++) {
    int cc = c * 256 + tid;
    int s = cc >> 9, rem = cc & 511, row = rem >> 2, k0 = (rem & 3) * 8;
    gload16(Kz + (long)(n0 + row) * 64 + s * 32 + k0, &Ks[cc * 8]);
  }
  if (tid < 128)
    ((uint4*)Ms)[tid] =
        *(const uint4*)(Mpk + ((long)b << 17) + (long)(q0 + tid) * 128 + (n0 >> 3));
  __syncthreads();

  v4f sacc[4][4];
  const v4f zero4 = {0.f, 0.f, 0.f, 0.f};
#pragma unroll
  for (int i = 0; i < 4; i++)
#pragma unroll
    for (int j = 0; j < 4; j++) sacc[i][j] = zero4;
#pragma unroll
  for (int s = 0; s < 2; s++) {
    v8s af[4], bf[4];
#pragma unroll
    for (int i = 0; i < 4; i++)
      af[i] = *(const v8s*)&Qs[s * 4096 + (wm + i * 16 + (lane & 15)) * 32 + (lane >> 4) * 8];
#pragma unroll
    for (int j = 0; j < 4; j++)
      bf[j] = *(const v8s*)&Ks[s * 4096 + (wn + j * 16 + (lane & 15)) * 32 + (lane >> 4) * 8];
#pragma unroll
    for (int i = 0; i < 4; i++)
#pragma unroll
      for (int j = 0; j < 4; j++)
        sacc[i][j] = __builtin_amdgcn_mfma_f32_16x16x32_bf16(af[i], bf[j], sacc[i][j], 0, 0, 0);
  }
  __syncthreads();  // all Qs/Ks reads done before Ps overwrite

  // epilogue: mask -> exp -> P(LDS) + column partial sums -> atomics
#pragma unroll
  for (int j = 0; j < 4; j++) {
    int col = wn + j * 16 + (lane & 15);
    float csum = 0.f;
#pragma unroll
    for (int i = 0; i < 4; i++) {
      int mlb = wm + i * 16 + ((lane >> 4) << 2);
#pragma unroll
      for (int r = 0; r < 4; r++) {
        int ml = mlb + r;
        bool mk = (Ms[ml * 16 + (col >> 3)] >> (col & 7)) & 1;
        // masked: exp(-1000/8) underflows fp32 to exactly 0 (matches ref-on-bf16 path)
        float ev = mk ? __expf(sacc[i][j][r] * 0.125f) : 0.f;
        u16 eb = f2bf(ev);
        Ps[ml * 136 + col] = eb;
        csum += bf2f(eb);
      }
    }
    csum += __shfl_xor(csum, 16);
    csum += __shfl_xor(csum, 32);
    if (lane < 16) atomicAdd(&rc[(zl << 10) + n0 + col], csum);
  }
  __syncthreads();

  // coalesced E store: 16 B/lane, row-major
  u16* Ez = E + ((long)zl << 20);
#pragma unroll
  for (int it = 0; it < 8; it++) {
    int idx = it * 256 + tid;
    int row = idx >> 4, c16 = (idx & 15) * 8;
    *(uint4*)(Ez + (long)(q0 + row) * 1024 + n0 + c16) = *(const uint4*)(&Ps[row * 136 + c16]);
  }
}

// ---- fallback two-pass attention (no E), proven in R4 ----
__global__ __launch_bounds__(256, 2)
void attn_colsum(const u16* __restrict__ Q, const u16* __restrict__ Kb,
                 const unsigned char* __restrict__ Mb, float* __restrict__ rc)
{
  __shared__ u16 Qs[2 * 128 * 32];
  __shared__ u16 Ks[2 * 128 * 32];
  const int tid = threadIdx.x, lane = tid & 63, wave = tid >> 6;
  const int wm = (wave >> 1) * 64, wn = (wave & 1) * 64;
  const int z = blockIdx.y, q0 = blockIdx.x * 128, b = z >> 4;
  const u16* Qz = Q + ((long)z << 16);
  const u16* Kz = Kb + ((long)z << 16);
  const unsigned char* Mz = Mb + ((long)b << 20);

#pragma unroll
  for (int c = 0; c < 4; c++) {
    int cc = c * 256 + tid;
    int s = cc >> 9, rem = cc & 511, row = rem >> 2, k0 = (rem & 3) * 8;
    gload16(Qz + (long)(q0 + row) * 64 + s * 32 + k0, &Qs[cc * 8]);
  }

  for (int nt = 0; nt < 8; nt++) {
    int n0 = nt * 128;
#pragma unroll
    for (int c = 0; c < 4; c++) {
      int cc = c * 256 + tid;
      int s = cc >> 9, rem = cc & 511, row = rem >> 2, k0 = (rem & 3) * 8;
      gload16(Kz + (long)(n0 + row) * 64 + s * 32 + k0, &Ks[cc * 8]);
    }
    __syncthreads();

    v4f sacc[4][4];
    const v4f zero4 = {0.f, 0.f, 0.f, 0.f};
#pragma unroll
    for (int i = 0; i < 4; i++)
#pragma unroll
      for (int j = 0; j < 4; j++) sacc[i][j] = zero4;
#pragma unroll
    for (int s = 0; s < 2; s++) {
      v8s af[4], bf[4];
#pragma unroll
      for (int i = 0; i < 4; i++)
        af[i] = *(const v8s*)&Qs[s * 4096 + (wm + i * 16 + (lane & 15)) * 32 + (lane >> 4) * 8];
#pragma unroll
      for (int j = 0; j < 4; j++)
        bf[j] = *(const v8s*)&Ks[s * 4096 + (wn + j * 16 + (lane & 15)) * 32 + (lane >> 4) * 8];
#pragma unroll
      for (int i = 0; i < 4; i++)
#pragma unroll
        for (int j = 0; j < 4; j++)
          sacc[i][j] = __builtin_amdgcn_mfma_f32_16x16x32_bf16(af[i], bf[j], sacc[i][j], 0, 0, 0);
    }

#pragma unroll
    for (int j = 0; j < 4; j++) {
      int n = n0 + wn + j * 16 + (lane & 15);
      float csum = 0.f;
#pragma unroll
      for (int i = 0; i < 4; i++) {
        int mbase = q0 + wm + i * 16 + ((lane >> 4) << 2);
#pragma unroll
        for (int r = 0; r < 4; r++) {
          int m = mbase + r;
          bool mk = Mz[(long)m * 1024 + n] != 0;
          float sv = mk ? sacc[i][j][r] : -1000.0f;
          csum += bf2f(f2bf(__expf(sv * 0.125f)));
        }
      }
      csum += __shfl_xor(csum, 16);
      csum += __shfl_xor(csum, 32);
      if (lane < 16) atomicAdd(&rc[(z << 10) + n], csum);
    }
    __syncthreads();
  }
}

__global__ __launch_bounds__(256, 2)
void attn_pv(const u16* __restrict__ Q, const u16* __restrict__ Kb,
             const u16* __restrict__ vT, const unsigned char* __restrict__ Mb,
             u16* __restrict__ oc)
{
  __shared__ u16 Ks[2 * 128 * 32];
  __shared__ u16 Vs[4 * 64 * 32];
  __shared__ u16 Ps[4 * 128 * 32];
  const int tid = threadIdx.x, lane = tid & 63, wave = tid >> 6;
  const int wm = (wave >> 1) * 64;
  const int wn = (wave & 1) * 64;
  const int wnv = (wave & 1) * 32;
  const int z = blockIdx.y, q0 = blockIdx.x * 128, b = z >> 4, h = z & 15;
  const u16* Qz = Q + ((long)z << 16);
  const u16* Kz = Kb + ((long)z << 16);
  const u16* Vz = vT + ((long)z << 16);
  const unsigned char* Mz = Mb + ((long)b << 20);

#pragma unroll
  for (int c = 0; c < 4; c++) {
    int cc = c * 256 + tid;
    int s = cc >> 9, rem = cc & 511, row = rem >> 2, k0 = (rem & 3) * 8;
    gload16(Qz + (long)(q0 + row) * 64 + s * 32 + k0, &Ks[cc * 8]);
  }
  __syncthreads();
  v8s qf[4][2];
#pragma unroll
  for (int i = 0; i < 4; i++)
#pragma unroll
    for (int s = 0; s < 2; s++)
      qf[i][s] = *(const v8s*)&Ks[s * 4096 + (wm + i * 16 + (lane & 15)) * 32 + (lane >> 4) * 8];
  __syncthreads();

  v4f oacc[4][2];
  const v4f zero4 = {0.f, 0.f, 0.f, 0.f};
#pragma unroll
  for (int i = 0; i < 4; i++)
#pragma unroll
    for (int j = 0; j < 2; j++) oacc[i][j] = zero4;

  for (int nt = 0; nt < 8; nt++) {
    int n0 = nt * 128;
#pragma unroll
    for (int c = 0; c < 4; c++) {
      int cc = c * 256 + tid;
      int s = cc >> 9, rem = cc & 511, row = rem >> 2, k0 = (rem & 3) * 8;
      gload16(Kz + (long)(n0 + row) * 64 + s * 32 + k0, &Ks[cc * 8]);
    }
#pragma unroll
    for (int c = 0; c < 4; c++) {
      int cc = c * 256 + tid;
      int s = cc >> 8, rem = cc & 255, v = rem >> 2, k0 = (rem & 3) * 8;
      gload16(Vz + (long)v * 1024 + n0 + s * 32 + k0, &Vs[cc * 8]);
    }
    __syncthreads();

    v4f sacc[4][4];
#pragma unroll
    for (int i = 0; i < 4; i++)
#pragma unroll
      for (int j = 0; j < 4; j++) sacc[i][j] = zero4;
#pragma unroll
    for (int s = 0; s < 2; s++) {
      v8s bf[4];
#pragma unroll
      for (int j = 0; j < 4; j++)
        bf[j] = *(const v8s*)&Ks[s * 4096 + (wn + j * 16 + (lane & 15)) * 32 + (lane >> 4) * 8];
#pragma unroll
      for (int i = 0; i < 4; i++)
#pragma unroll
        for (int j = 0; j < 4; j++)
          sacc[i][j] = __builtin_amdgcn_mfma_f32_16x16x32_bf16(qf[i][s], bf[j], sacc[i][j], 0, 0, 0);
    }

#pragma unroll
    for (int i = 0; i < 4; i++) {
      int mlb = wm + i * 16 + ((lane >> 4) << 2);
#pragma unroll
      for (int j = 0; j < 4; j++) {
        int col = wn + j * 16 + (lane & 15);
        int gn = n0 + col;
#pragma unroll
        for (int r = 0; r < 4; r++) {
          int ml = mlb + r;
          bool mk = Mz[(long)(q0 + ml) * 1024 + gn] != 0;
          float sv = mk ? sacc[i][j][r] : -1000.0f;
          Ps[(col >> 5) * 4096 + ml * 32 + (col & 31)] = f2bf(__expf(sv * 0.125f));
        }
      }
    }
    __syncthreads();

#pragma unroll
    for (int s = 0; s < 4; s++) {
      v8s vf[2];
#pragma unroll
      for (int j = 0; j < 2; j++)
        vf[j] = *(const v8s*)&Vs[s * 2048 + (wnv + j * 16 + (lane & 15)) * 32 + (lane >> 4) * 8];
#pragma unroll
      for (int i = 0; i < 4; i++) {
        v8s pf = *(const v8s*)&Ps[s * 4096 + (wm + i * 16 + (lane & 15)) * 32 + (lane >> 4) * 8];
#pragma unroll
        for (int j = 0; j < 2; j++)
          oacc[i][j] = __builtin_amdgcn_mfma_f32_16x16x32_bf16(pf, vf[j], oacc[i][j], 0, 0, 0);
      }
    }
    __syncthreads();
  }

#pragma unroll
  for (int i = 0; i < 4; i++) {
    int mbase = q0 + wm + i * 16 + ((lane >> 4) << 2);
#pragma unroll
    for (int j = 0; j < 2; j++) {
      int n = wnv + j * 16 + (lane & 15);
#pragma unroll
      for (int r = 0; r < 4; r++) {
        int m = mbase + r;
        oc[((long)(b * 1024 + m) << 10) + h * 64 + n] = f2bf(oacc[i][j][r]);
      }
    }
  }
}

// Transpose V [z,s,e] -> vT [z,e,s], scaling column s by 1/colsum(s).
__global__ __launch_bounds__(256)
void transpose_scale(const u16* __restrict__ V, const float* __restrict__ rc,
                     u16* __restrict__ vT)
{
  __shared__ u16 t[64 * 66];
  __shared__ float rl[64];
  const int zl = blockIdx.y;
  const int s0 = blockIdx.x * 64;
  const int tid = threadIdx.x;
  const int r = tid >> 2, cg = (tid & 3) << 4;
  const u16* src = V + ((long)zl << 16) + (long)(s0 + r) * 64 + cg;
  v4u16 a0 = *(const v4u16*)(src);
  v4u16 a1 = *(const v4u16*)(src + 4);
  v4u16 a2 = *(const v4u16*)(src + 8);
  v4u16 a3 = *(const v4u16*)(src + 12);
  if (tid < 64) rl[tid] = 1.f / rc[(zl << 10) + s0 + tid];
  u16 tmp[16] = {(u16)a0.x, (u16)a0.y, (u16)a0.z, (u16)a0.w,
                 (u16)a1.x, (u16)a1.y, (u16)a1.z, (u16)a1.w,
                 (u16)a2.x, (u16)a2.y, (u16)a2.z, (u16)a2.w,
                 (u16)a3.x, (u16)a3.y, (u16)a3.z, (u16)a3.w};
#pragma unroll
  for (int i = 0; i < 16; i++) t[(cg + i) * 66 + r] = tmp[i];
  __syncthreads();
  const int e = tid >> 2, sg = (tid & 3) << 4;
  u16* dst = vT + ((long)zl << 16) + (long)e * 1024 + s0 + sg;
  v4u16 o;
#pragma unroll
  for (int q = 0; q < 4; q++) {
#pragma unroll
    for (int w = 0; w < 4; w++) {
      float f = bf2f(t[e * 66 + sg + q * 4 + w]) * rl[sg + q * 4 + w];
      ((u16*)&o)[w] = f2bf(f);
    }
    *(v4u16*)(dst + q * 4) = o;
  }
}

// LayerNorm over 1024 cols; one block per row.
__global__ __launch_bounds__(256)
void ln_kernel(const float* __restrict__ in, const float* __restrict__ gam,
               const float* __restrict__ bet, float* __restrict__ outf,
               u16* __restrict__ outb)
{
  long row = blockIdx.x;
  v4f v = *(const v4f*)(in + (row << 10) + (threadIdx.x << 2));
  float s = v.x + v.y + v.z + v.w;
  float s2 = v.x * v.x + v.y * v.y + v.z * v.z + v.w * v.w;
#pragma unroll
  for (int o = 32; o > 0; o >>= 1) { s += __shfl_down(s, o); s2 += __shfl_down(s2, o); }
  __shared__ float red[8];
  int wv_ = threadIdx.x >> 6, ln = threadIdx.x & 63;
  if (ln == 0) { red[wv_] = s; red[4 + wv_] = s2; }
  __syncthreads();
  float S1 = red[0] + red[1] + red[2] + red[3];
  float S2 = red[4] + red[5] + red[6] + red[7];
  float mu = S1 * (1.f / 1024.f);
  float var = S2 * (1.f / 1024.f) - mu * mu;
  float rstd = rsqrtf(var + 1e-5f);
  v4f g4 = *(const v4f*)(gam + (threadIdx.x << 2));
  v4f b4 = *(const v4f*)(bet + (threadIdx.x << 2));
  v4f o4;
  o4.x = (v.x - mu) * rstd * g4.x + b4.x;
  o4.y = (v.y - mu) * rstd * g4.y + b4.y;
  o4.z = (v.z - mu) * rstd * g4.z + b4.z;
  o4.w = (v.w - mu) * rstd * g4.w + b4.w;
  if (outf) *(v4f*)(outf + (row << 10) + (threadIdx.x << 2)) = o4;
  if (outb) {
    v4u16 u;
    u.x = f2bf(o4.x); u.y = f2bf(o4.y); u.z = f2bf(o4.z); u.w = f2bf(o4.w);
    *(v4u16*)(outb + (row << 10) + (threadIdx.x << 2)) = u;
  }
}

__global__ __launch_bounds__(256)
void cvt_bf16(const float* __restrict__ in, u16* __restrict__ out, int n4)
{
  int i = blockIdx.x * 256 + threadIdx.x;
  if (i >= n4) return;
  v4f v = ((const v4f*)in)[i];
  v4u16 u;
  u.x = f2bf(v.x); u.y = f2bf(v.y); u.z = f2bf(v.z); u.w = f2bf(v.w);
  ((v4u16*)out)[i] = u;
}

// Pack wq/wk/wv [h][d][e] -> B matrix [n = w*1024 + h*64 + e][d] bf16.
__global__ __launch_bounds__(256)
void pack_qkvw(const float* __restrict__ wq, const float* __restrict__ wk,
               const float* __restrict__ wv, u16* __restrict__ out)
{
  int i = blockIdx.x * 256 + threadIdx.x;  // 3*2^20 total
  int w = i >> 20, r = i & 1048575;
  int e = r & 63, d = (r >> 6) & 1023, h = r >> 16;
  const float* src = (w == 0) ? wq : ((w == 1) ? wk : wv);
  float v = src[(((long)h << 10) + d) * 64 + e];
  out[((((long)w << 10) + (h << 6) + e) << 10) + d] = f2bf(v);
}

// Detect whether mask is int32 (bytes at i%4!=0 all zero) or bool bytes.
__global__ void detect_mask_kernel(const unsigned char* __restrict__ m, int* __restrict__ flag)
{
  if (threadIdx.x == 0 && blockIdx.x == 0) {
    int nz = 0;
    for (int i = 0; i < 256; i++)
      if ((i & 3) != 0 && m[i] != 0) nz++;
    *flag = (nz == 0) ? 1 : 0;
  }
}

// Canonicalize mask into u8 {0,1} bytes (fallback path).
__global__ __launch_bounds__(256)
void canon_mask(const unsigned char* __restrict__ m, const int* __restrict__ flag,
                unsigned char* __restrict__ out)
{
  int i = blockIdx.x * 256 + threadIdx.x;
  uchar4 o;
  if (*flag) {
    const int* mi = (const int*)m;
    o.x = mi[i * 4 + 0] != 0; o.y = mi[i * 4 + 1] != 0;
    o.z = mi[i * 4 + 2] != 0; o.w = mi[i * 4 + 3] != 0;
  } else {
    o = ((const uchar4*)m)[i];
  }
  ((uchar4*)out)[i] = o;
}

// Bit-pack mask: out word g covers entries [32g, 32g+32), bit = entry&31.
__global__ __launch_bounds__(256)
void canon_pack(const unsigned char* __restrict__ m, const int* __restrict__ flag,
                unsigned int* __restrict__ out)
{
  int g = blockIdx.x * 256 + threadIdx.x;  // 262144 total
  unsigned int bits = 0;
  if (*flag) {
    const int* mi = (const int*)m + (long)g * 32;
#pragma unroll
    for (int i = 0; i < 32; i++) bits |= (mi[i] != 0 ? 1u : 0u) << i;
  } else {
    const unsigned char* mb = m + (long)g * 32;
#pragma unroll
    for (int i = 0; i < 32; i++) bits |= (mb[i] != 0 ? 1u : 0u) << i;
  }
  out[g] = bits;
}

extern "C" void kernel_launch(void* const* d_in, const int* in_sizes, int n_in,
                              void* d_out, int out_size, void* d_ws, size_t ws_size,
                              hipStream_t stream)
{
  const float* x     = (const float*)d_in[0];
  const unsigned char* mask = (const unsigned char*)d_in[1];
  const float* wq    = (const float*)d_in[2];
  const float* wk    = (const float*)d_in[3];
  const float* wv    = (const float*)d_in[4];
  const float* fc_w  = (const float*)d_in[5];
  const float* fc_b  = (const float*)d_in[6];
  const float* w1    = (const float*)d_in[7];
  const float* b1    = (const float*)d_in[8];
  const float* w2    = (const float*)d_in[9];
  const float* b2    = (const float*)d_in[10];
  const float* ln1_g = (const float*)d_in[11];
  const float* ln1_b = (const float*)d_in[12];
  const float* ln2_g = (const float*)d_in[13];
  const float* ln2_b = (const float*)d_in[14];
  (void)in_sizes; (void)n_in; (void)out_size;

  // ---- workspace map (aliased lifetimes) ----
  const size_t MB = 1ull << 20;
  char* ws = (char*)d_ws;
  int*   mflag = (int*)ws;                  // 4 B
  float* rc    = (float*)(ws + 65536);      // 512 KB
  unsigned char* Mpk = (unsigned char*)(ws + 1 * MB);  // 1 MB bit-packed mask
  u16*   bqkv  = (u16*)(ws + 2 * MB);       // 6 MB
  u16*   fcb   = (u16*)(ws + 8 * MB);       // 2 MB
  u16*   w1b   = (u16*)(ws + 10 * MB);      // 8 MB
  u16*   w2b   = (u16*)(ws + 18 * MB);      // 8 MB
  u16*   xb    = (u16*)(ws + 26 * MB);      // 16 MB -> x1b alias
  u16*   x1b   = xb;
  u16*   Qb    = (u16*)(ws + 42 * MB);      // 16 MB
  u16*   Kb    = (u16*)(ws + 58 * MB);      // 16 MB
  u16*   Vb    = (u16*)(ws + 74 * MB);      // 16 MB ([z,s,e])
  u16*   vT    = (u16*)(ws + 90 * MB);      // 16 MB ([z,e,s], scaled)
  u16*   oc    = (u16*)(ws + 106 * MB);     // 16 MB
  u16*   h1    = (u16*)(ws + 42 * MB);      // 64 MB alias Qb..vT (post-attention)
  float* r1    = (float*)(ws + 122 * MB);   // 32 MB (post-attention)
  unsigned char* Mb = (unsigned char*)(ws + 122 * MB);  // 8 MB (fallback attn)
  u16*   E     = (u16*)(ws + 122 * MB);     // 2*CZ MB (new path, aliases r1)

  // chunk tier by workspace: peak = 122 MB + 2*CZ MB
  int CZ = 0;
  if      (ws_size >= 378 * MB) CZ = 128;
  else if (ws_size >= 250 * MB) CZ = 64;
  else if (ws_size >= 186 * MB) CZ = 32;
  else if (ws_size >= 154 * MB) CZ = 16;

  detect_mask_kernel<<<1, 64, 0, stream>>>(mask, mflag);
  if (CZ > 0) canon_pack<<<1024, 256, 0, stream>>>(mask, mflag, (unsigned int*)Mpk);
  else        canon_mask<<<8192, 256, 0, stream>>>(mask, mflag, Mb);

  cvt_bf16<<<8192, 256, 0, stream>>>(x, xb, 2097152);
  pack_qkvw<<<12288, 256, 0, stream>>>(wq, wk, wv, bqkv);
  cvt_bf16<<<1024, 256, 0, stream>>>(fc_w, fcb, 262144);
  cvt_bf16<<<4096, 256, 0, stream>>>(w1, w1b, 1048576);
  cvt_bf16<<<4096, 256, 0, stream>>>(w2, w2b, 1048576);

  // QKV projections: [8192 x 1024] x [3072 x 1024]^T ; tiles 24x64
  {
    EpArgs ep = {};
    ep.q = Qb; ep.k = Kb; ep.v = Vb;
    gemm_nt<128, 128, 4, 4, MODE_QKV><<<dim3(24 * 64, 1), 256, 0, stream>>>(
        xb, 1024, 0, bqkv, 1024, 0, 1024, 3072, 24, 64, ep);
  }

  hipMemsetAsync(rc, 0, 128 * 1024 * 4, stream);
  if (CZ > 0) {
    for (int z0 = 0; z0 < 128; z0 += CZ) {
      attn_score<<<dim3(8, 8, CZ), 256, 0, stream>>>(
          Qb + (long)z0 * 65536, Kb + (long)z0 * 65536, Mpk,
          rc + (long)z0 * 1024, E, z0);
      transpose_scale<<<dim3(16, CZ), 256, 0, stream>>>(
          Vb + (long)z0 * 65536, rc + (long)z0 * 1024, vT + (long)z0 * 65536);
      EpArgs ep = {};
      ep.outb = oc; ep.z0 = z0;
      gemm_nt<128, 64, 4, 2, MODE_PV><<<dim3(8, CZ), 256, 0, stream>>>(
          E, 1024, 1048576, vT + (long)z0 * 65536, 1024, 65536,
          1024, 64, 1, 8, ep);
    }
  } else {
    attn_colsum<<<dim3(8, 128), 256, 0, stream>>>(Qb, Kb, Mb, rc);
    transpose_scale<<<dim3(16, 128), 256, 0, stream>>>(Vb, rc, vT);
    attn_pv<<<dim3(8, 128), 256, 0, stream>>>(Qb, Kb, vT, Mb, oc);
  }

  // att = oc @ fc_w^T + fc_b + x -> r1 (fp32)
  {
    EpArgs ep = {};
    ep.bias = fc_b; ep.res = x; ep.outf = r1;
    gemm_nt<128, 128, 4, 4, MODE_BIAS_RES><<<dim3(8 * 64, 1), 256, 0, stream>>>(
        oc, 1024, 0, fcb, 1024, 0, 1024, 1024, 8, 64, ep);
  }
  ln_kernel<<<8192, 256, 0, stream>>>(r1, ln1_g, ln1_b, (float*)nullptr, x1b);
  // h1 = relu(x1 @ w1^T + b1) bf16
  {
    EpArgs ep = {};
    ep.bias = b1; ep.outb = h1;
    gemm_nt<128, 128, 4, 4, MODE_BIAS_RELU><<<dim3(32 * 64, 1), 256, 0, stream>>>(
        x1b, 1024, 0, w1b, 1024, 0, 1024, 4096, 32, 64, ep);
  }
  // r2 = h1 @ w2^T + b2 + x1(bf16) -> r1 (fp32)
  {
    EpArgs ep = {};
    ep.bias = b2; ep.res_bf = x1b; ep.outf = r1;
    gemm_nt<128, 128, 4, 4, MODE_BIAS_RES><<<dim3(8 * 64, 1), 256, 0, stream>>>(
        h1, 4096, 0, w2b, 4096, 0, 4096, 1024, 8, 64, ep);
  }
  ln_kernel<<<8192, 256, 0, stream>>>(r1, ln2_g, ln2_b, (float*)d_out, (u16*)nullptr);
}

// Round 6
// 638.478 us; speedup vs baseline: 2.1087x; 1.1176x over previous
//
#include <hip/hip_runtime.h>
#include <stdint.h>

#define DEV static __device__ __forceinline__

typedef unsigned short u16;
typedef __attribute__((ext_vector_type(8))) short v8s;    // 8 x bf16 MFMA operand
typedef __attribute__((ext_vector_type(4))) float v4f;
typedef __attribute__((ext_vector_type(4))) unsigned short v4u16;

DEV u16 f2bf(float f) {
  union { float f; unsigned u; } c; c.f = f;
  unsigned r = c.u + 0x7FFFu + ((c.u >> 16) & 1u);
  return (u16)(r >> 16);
}
DEV float bf2f(u16 h) {
  union { unsigned u; float f; } c; c.u = ((unsigned)h) << 16;
  return c.f;
}

// async global->LDS, 16B per lane; LDS dest = wave-uniform base + lane*16.
DEV void gload16(const u16* g, u16* l) {
  __builtin_amdgcn_global_load_lds(
      (const __attribute__((address_space(1))) unsigned int*)g,
      (__attribute__((address_space(3))) unsigned int*)l, 16, 0, 0);
}

enum { MODE_QKV = 0, MODE_PV = 2, MODE_BIAS_RES = 3, MODE_BIAS_RELU = 4, MODE_PARTIAL = 5 };

struct EpArgs {
  const float* bias;          // BIAS_*
  const float* res;           // BIAS_RES fp32 residual (or null)
  const u16* res_bf;          // BIAS_RES bf16 residual (used if res==null)
  float* outf;                // BIAS_RES
  u16* outb;                  // PV/BIAS_RELU/PARTIAL slice 0
  u16* outb2;                 // PARTIAL slice 1
  u16* q; u16* k; u16* v;     // QKV scatter (all [z,s,e])
  int z0;                     // chunk base z for PV
};

// NT GEMM: C[m][n] = sum_k A[m][k]*B[n][k]. BK=32, 256 thr = 4 waves (2x2).
// Tiles flattened into grid.x, XCD-aware swizzle (nby multiple of 8). z = blockIdx.y.
// MODE_PARTIAL: z = K-slice index; A/B advanced by z*sA/z*sB elements; slice K
// passed as K; bf16 partial written to outb (z=0) / outb2 (z=1).
template <int BM, int BN, int FM, int FN, int MODE>
__global__ __launch_bounds__(256, 2)
void gemm_nt(const u16* __restrict__ A, int lda, long sA,
             const u16* __restrict__ B, int ldb, long sB,
             int K, int N, int nbx, int nby, EpArgs ep)
{
  __shared__ u16 As[BM * 32];
  __shared__ u16 Bs[BN * 32];

  const int tid  = threadIdx.x;
  const int lane = tid & 63;
  const int wave = tid >> 6;
  const int wm = (wave >> 1) * (FM * 16);
  const int wn = (wave & 1) * (FN * 16);

  const int id = blockIdx.x;
  const int nby8 = nby >> 3;
  const int c8 = id & 7, jj = id >> 3;
  const int tm = ((jj % nby8) * 8 + c8) * BM;
  const int tn = (jj / nby8) * BN;
  const int z  = blockIdx.y;

  const u16* Az = A + (long)z * sA;
  const u16* Bz = B + (long)z * sB;

  v4f acc[FM][FN];
  const v4f zero4 = {0.f, 0.f, 0.f, 0.f};
#pragma unroll
  for (int i = 0; i < FM; i++)
#pragma unroll
    for (int j = 0; j < FN; j++) acc[i][j] = zero4;

  for (int kt = 0; kt < K; kt += 32) {
#pragma unroll
    for (int c = 0; c < BM * 4; c += 256) {
      int cc = c + tid;
      int row = cc >> 2, kk = (cc & 3) * 8;
      gload16(Az + (long)(tm + row) * lda + kt + kk, &As[cc * 8]);
    }
#pragma unroll
    for (int c = 0; c < BN * 4; c += 256) {
      int cc = c + tid;
      int row = cc >> 2, kk = (cc & 3) * 8;
      gload16(Bz + (long)(tn + row) * ldb + kt + kk, &Bs[cc * 8]);
    }
    __syncthreads();

    v8s af[FM], bfr[FN];
#pragma unroll
    for (int i = 0; i < FM; i++)
      af[i] = *(const v8s*)&As[(wm + i * 16 + (lane & 15)) * 32 + (lane >> 4) * 8];
#pragma unroll
    for (int j = 0; j < FN; j++)
      bfr[j] = *(const v8s*)&Bs[(wn + j * 16 + (lane & 15)) * 32 + (lane >> 4) * 8];
#pragma unroll
    for (int i = 0; i < FM; i++)
#pragma unroll
      for (int j = 0; j < FN; j++)
        acc[i][j] = __builtin_amdgcn_mfma_f32_16x16x32_bf16(af[i], bfr[j], acc[i][j], 0, 0, 0);
    __syncthreads();
  }

  bool res_is_f32 = false;
  if constexpr (MODE == MODE_BIAS_RES) res_is_f32 = (ep.res != nullptr);
  u16* pdst = nullptr;
  if constexpr (MODE == MODE_PARTIAL) pdst = z ? ep.outb2 : ep.outb;

  // C/D layout: col = lane&15, row = (lane>>4)*4 + r
#pragma unroll
  for (int i = 0; i < FM; i++) {
    int mbase = tm + wm + i * 16 + ((lane >> 4) << 2);
#pragma unroll
    for (int j = 0; j < FN; j++) {
      int n = tn + wn + j * 16 + (lane & 15);
#pragma unroll
      for (int r = 0; r < 4; r++) {
        float val = acc[i][j][r];
        int m = mbase + r;
        if constexpr (MODE == MODE_QKV) {
          int b = m >> 10, s = m & 1023;
          int w = n >> 10, rr = n & 1023, h = rr >> 6, e = rr & 63;
          long idx = (((long)(b * 16 + h) << 10) + s) * 64 + e;  // [z,s,e]
          u16* dst = (w == 0) ? ep.q : (w == 1) ? ep.k : ep.v;
          dst[idx] = f2bf(val);
        } else if constexpr (MODE == MODE_PV) {
          int zg = ep.z0 + z;
          int b = zg >> 4, h = zg & 15;
          ep.outb[((long)(b * 1024 + m) << 10) + h * 64 + n] = f2bf(val);
        } else if constexpr (MODE == MODE_BIAS_RES) {
          long idx = (long)m * N + n;
          float rres = res_is_f32 ? ep.res[idx] : bf2f(ep.res_bf[idx]);
          ep.outf[idx] = val + ep.bias[n] + rres;
        } else if constexpr (MODE == MODE_BIAS_RELU) {
          float v2 = val + ep.bias[n];
          ep.outb[(long)m * N + n] = f2bf(fmaxf(v2, 0.f));
        } else if constexpr (MODE == MODE_PARTIAL) {
          pdst[(long)m * N + n] = f2bf(val);
        }
      }
    }
  }
}

// ---- attention pass 1: S = Q K^T, E = exp(masked/8) bf16, colsum atomics,
// coalesced E store. One 128x128 tile per block; grid (8 ktile, 8 qtile, CZ).
__global__ __launch_bounds__(256, 4)
void attn_score(const u16* __restrict__ Q, const u16* __restrict__ Kb,
                const unsigned char* __restrict__ Mpk, float* __restrict__ rc,
                u16* __restrict__ E, int z0)
{
  __shared__ u16 sh[17408];           // Q/K staging (32 KB), reused as P (stride 136)
  __shared__ unsigned char Ms[2048];  // mask bits for this 128x128 tile
  const int tid = threadIdx.x, lane = tid & 63, wave = tid >> 6;
  const int wm = (wave >> 1) * 64, wn = (wave & 1) * 64;
  const int zl = blockIdx.z, q0 = blockIdx.y * 128, n0 = blockIdx.x * 128;
  const int b = (z0 + zl) >> 4;
  const u16* Qz = Q + ((long)zl << 16);
  const u16* Kz = Kb + ((long)zl << 16);
  u16* Qs = sh;           // [2 slabs][128][32]
  u16* Ks = sh + 8192;
  u16* Ps = sh;           // reuse after MFMA, row stride 136 u16

#pragma unroll
  for (int c = 0; c < 4; c++) {
    int cc = c * 256 + tid;
    int s = cc >> 9, rem = cc & 511, row = rem >> 2, k0 = (rem & 3) * 8;
    gload16(Qz + (long)(q0 + row) * 64 + s * 32 + k0, &Qs[cc * 8]);
  }
#pragma unroll
  for (int c = 0; c < 4; c++) {
    int cc = c * 256 + tid;
    int s = cc >> 9, rem = cc & 511, row = rem >> 2, k0 = (rem & 3) * 8;
    gload16(Kz + (long)(n0 + row) * 64 + s * 32 + k0, &Ks[cc * 8]);
  }
  if (tid < 128)
    ((uint4*)Ms)[tid] =
        *(const uint4*)(Mpk + ((long)b << 17) + (long)(q0 + tid) * 128 + (n0 >> 3));
  __syncthreads();

  v4f sacc[4][4];
  const v4f zero4 = {0.f, 0.f, 0.f, 0.f};
#pragma unroll
  for (int i = 0; i < 4; i++)
#pragma unroll
    for (int j = 0; j < 4; j++) sacc[i][j] = zero4;
#pragma unroll
  for (int s = 0; s < 2; s++) {
    v8s af[4], bf[4];
#pragma unroll
    for (int i = 0; i < 4; i++)
      af[i] = *(const v8s*)&Qs[s * 4096 + (wm + i * 16 + (lane & 15)) * 32 + (lane >> 4) * 8];
#pragma unroll
    for (int j = 0; j < 4; j++)
      bf[j] = *(const v8s*)&Ks[s * 4096 + (wn + j * 16 + (lane & 15)) * 32 + (lane >> 4) * 8];
#pragma unroll
    for (int i = 0; i < 4; i++)
#pragma unroll
      for (int j = 0; j < 4; j++)
        sacc[i][j] = __builtin_amdgcn_mfma_f32_16x16x32_bf16(af[i], bf[j], sacc[i][j], 0, 0, 0);
  }
  __syncthreads();  // all Qs/Ks reads done before Ps overwrite

#pragma unroll
  for (int j = 0; j < 4; j++) {
    int col = wn + j * 16 + (lane & 15);
    float csum = 0.f;
#pragma unroll
    for (int i = 0; i < 4; i++) {
      int mlb = wm + i * 16 + ((lane >> 4) << 2);
#pragma unroll
      for (int r = 0; r < 4; r++) {
        int ml = mlb + r;
        bool mk = (Ms[ml * 16 + (col >> 3)] >> (col & 7)) & 1;
        float ev = mk ? __expf(sacc[i][j][r] * 0.125f) : 0.f;
        u16 eb = f2bf(ev);
        Ps[ml * 136 + col] = eb;
        csum += bf2f(eb);
      }
    }
    csum += __shfl_xor(csum, 16);
    csum += __shfl_xor(csum, 32);
    if (lane < 16) atomicAdd(&rc[(zl << 10) + n0 + col], csum);
  }
  __syncthreads();

  u16* Ez = E + ((long)zl << 20);
#pragma unroll
  for (int it = 0; it < 8; it++) {
    int idx = it * 256 + tid;
    int row = idx >> 4, c16 = (idx & 15) * 8;
    *(uint4*)(Ez + (long)(q0 + row) * 1024 + n0 + c16) = *(const uint4*)(&Ps[row * 136 + c16]);
  }
}

// ---- fallback two-pass attention (no E), proven in R4 ----
__global__ __launch_bounds__(256, 2)
void attn_colsum(const u16* __restrict__ Q, const u16* __restrict__ Kb,
                 const unsigned char* __restrict__ Mb, float* __restrict__ rc)
{
  __shared__ u16 Qs[2 * 128 * 32];
  __shared__ u16 Ks[2 * 128 * 32];
  const int tid = threadIdx.x, lane = tid & 63, wave = tid >> 6;
  const int wm = (wave >> 1) * 64, wn = (wave & 1) * 64;
  const int z = blockIdx.y, q0 = blockIdx.x * 128, b = z >> 4;
  const u16* Qz = Q + ((long)z << 16);
  const u16* Kz = Kb + ((long)z << 16);
  const unsigned char* Mz = Mb + ((long)b << 20);

#pragma unroll
  for (int c = 0; c < 4; c++) {
    int cc = c * 256 + tid;
    int s = cc >> 9, rem = cc & 511, row = rem >> 2, k0 = (rem & 3) * 8;
    gload16(Qz + (long)(q0 + row) * 64 + s * 32 + k0, &Qs[cc * 8]);
  }

  for (int nt = 0; nt < 8; nt++) {
    int n0 = nt * 128;
#pragma unroll
    for (int c = 0; c < 4; c++) {
      int cc = c * 256 + tid;
      int s = cc >> 9, rem = cc & 511, row = rem >> 2, k0 = (rem & 3) * 8;
      gload16(Kz + (long)(n0 + row) * 64 + s * 32 + k0, &Ks[cc * 8]);
    }
    __syncthreads();

    v4f sacc[4][4];
    const v4f zero4 = {0.f, 0.f, 0.f, 0.f};
#pragma unroll
    for (int i = 0; i < 4; i++)
#pragma unroll
      for (int j = 0; j < 4; j++) sacc[i][j] = zero4;
#pragma unroll
    for (int s = 0; s < 2; s++) {
      v8s af[4], bf[4];
#pragma unroll
      for (int i = 0; i < 4; i++)
        af[i] = *(const v8s*)&Qs[s * 4096 + (wm + i * 16 + (lane & 15)) * 32 + (lane >> 4) * 8];
#pragma unroll
      for (int j = 0; j < 4; j++)
        bf[j] = *(const v8s*)&Ks[s * 4096 + (wn + j * 16 + (lane & 15)) * 32 + (lane >> 4) * 8];
#pragma unroll
      for (int i = 0; i < 4; i++)
#pragma unroll
        for (int j = 0; j < 4; j++)
          sacc[i][j] = __builtin_amdgcn_mfma_f32_16x16x32_bf16(af[i], bf[j], sacc[i][j], 0, 0, 0);
    }

#pragma unroll
    for (int j = 0; j < 4; j++) {
      int n = n0 + wn + j * 16 + (lane & 15);
      float csum = 0.f;
#pragma unroll
      for (int i = 0; i < 4; i++) {
        int mbase = q0 + wm + i * 16 + ((lane >> 4) << 2);
#pragma unroll
        for (int r = 0; r < 4; r++) {
          int m = mbase + r;
          bool mk = Mz[(long)m * 1024 + n] != 0;
          float sv = mk ? sacc[i][j][r] : -1000.0f;
          csum += bf2f(f2bf(__expf(sv * 0.125f)));
        }
      }
      csum += __shfl_xor(csum, 16);
      csum += __shfl_xor(csum, 32);
      if (lane < 16) atomicAdd(&rc[(z << 10) + n], csum);
    }
    __syncthreads();
  }
}

__global__ __launch_bounds__(256, 2)
void attn_pv(const u16* __restrict__ Q, const u16* __restrict__ Kb,
             const u16* __restrict__ vT, const unsigned char* __restrict__ Mb,
             u16* __restrict__ oc)
{
  __shared__ u16 Ks[2 * 128 * 32];
  __shared__ u16 Vs[4 * 64 * 32];
  __shared__ u16 Ps[4 * 128 * 32];
  const int tid = threadIdx.x, lane = tid & 63, wave = tid >> 6;
  const int wm = (wave >> 1) * 64;
  const int wn = (wave & 1) * 64;
  const int wnv = (wave & 1) * 32;
  const int z = blockIdx.y, q0 = blockIdx.x * 128, b = z >> 4, h = z & 15;
  const u16* Qz = Q + ((long)z << 16);
  const u16* Kz = Kb + ((long)z << 16);
  const u16* Vz = vT + ((long)z << 16);
  const unsigned char* Mz = Mb + ((long)b << 20);

#pragma unroll
  for (int c = 0; c < 4; c++) {
    int cc = c * 256 + tid;
    int s = cc >> 9, rem = cc & 511, row = rem >> 2, k0 = (rem & 3) * 8;
    gload16(Qz + (long)(q0 + row) * 64 + s * 32 + k0, &Ks[cc * 8]);
  }
  __syncthreads();
  v8s qf[4][2];
#pragma unroll
  for (int i = 0; i < 4; i++)
#pragma unroll
    for (int s = 0; s < 2; s++)
      qf[i][s] = *(const v8s*)&Ks[s * 4096 + (wm + i * 16 + (lane & 15)) * 32 + (lane >> 4) * 8];
  __syncthreads();

  v4f oacc[4][2];
  const v4f zero4 = {0.f, 0.f, 0.f, 0.f};
#pragma unroll
  for (int i = 0; i < 4; i++)
#pragma unroll
    for (int j = 0; j < 2; j++) oacc[i][j] = zero4;

  for (int nt = 0; nt < 8; nt++) {
    int n0 = nt * 128;
#pragma unroll
    for (int c = 0; c < 4; c++) {
      int cc = c * 256 + tid;
      int s = cc >> 9, rem = cc & 511, row = rem >> 2, k0 = (rem & 3) * 8;
      gload16(Kz + (long)(n0 + row) * 64 + s * 32 + k0, &Ks[cc * 8]);
    }
#pragma unroll
    for (int c = 0; c < 4; c++) {
      int cc = c * 256 + tid;
      int s = cc >> 8, rem = cc & 255, v = rem >> 2, k0 = (rem & 3) * 8;
      gload16(Vz + (long)v * 1024 + n0 + s * 32 + k0, &Vs[cc * 8]);
    }
    __syncthreads();

    v4f sacc[4][4];
#pragma unroll
    for (int i = 0; i < 4; i++)
#pragma unroll
      for (int j = 0; j < 4; j++) sacc[i][j] = zero4;
#pragma unroll
    for (int s = 0; s < 2; s++) {
      v8s bf[4];
#pragma unroll
      for (int j = 0; j < 4; j++)
        bf[j] = *(const v8s*)&Ks[s * 4096 + (wn + j * 16 + (lane & 15)) * 32 + (lane >> 4) * 8];
#pragma unroll
      for (int i = 0; i < 4; i++)
#pragma unroll
        for (int j = 0; j < 4; j++)
          sacc[i][j] = __builtin_amdgcn_mfma_f32_16x16x32_bf16(qf[i][s], bf[j], sacc[i][j], 0, 0, 0);
    }

#pragma unroll
    for (int i = 0; i < 4; i++) {
      int mlb = wm + i * 16 + ((lane >> 4) << 2);
#pragma unroll
      for (int j = 0; j < 4; j++) {
        int col = wn + j * 16 + (lane & 15);
        int gn = n0 + col;
#pragma unroll
        for (int r = 0; r < 4; r++) {
          int ml = mlb + r;
          bool mk = Mz[(long)(q0 + ml) * 1024 + gn] != 0;
          float sv = mk ? sacc[i][j][r] : -1000.0f;
          Ps[(col >> 5) * 4096 + ml * 32 + (col & 31)] = f2bf(__expf(sv * 0.125f));
        }
      }
    }
    __syncthreads();

#pragma unroll
    for (int s = 0; s < 4; s++) {
      v8s vf[2];
#pragma unroll
      for (int j = 0; j < 2; j++)
        vf[j] = *(const v8s*)&Vs[s * 2048 + (wnv + j * 16 + (lane & 15)) * 32 + (lane >> 4) * 8];
#pragma unroll
      for (int i = 0; i < 4; i++) {
        v8s pf = *(const v8s*)&Ps[s * 4096 + (wm + i * 16 + (lane & 15)) * 32 + (lane >> 4) * 8];
#pragma unroll
        for (int j = 0; j < 2; j++)
          oacc[i][j] = __builtin_amdgcn_mfma_f32_16x16x32_bf16(pf, vf[j], oacc[i][j], 0, 0, 0);
      }
    }
    __syncthreads();
  }

#pragma unroll
  for (int i = 0; i < 4; i++) {
    int mbase = q0 + wm + i * 16 + ((lane >> 4) << 2);
#pragma unroll
    for (int j = 0; j < 2; j++) {
      int n = wnv + j * 16 + (lane & 15);
#pragma unroll
      for (int r = 0; r < 4; r++) {
        int m = mbase + r;
        oc[((long)(b * 1024 + m) << 10) + h * 64 + n] = f2bf(oacc[i][j][r]);
      }
    }
  }
}

// Transpose V [z,s,e] -> vT [z,e,s], scaling column s by 1/colsum(s).
__global__ __launch_bounds__(256)
void transpose_scale(const u16* __restrict__ V, const float* __restrict__ rc,
                     u16* __restrict__ vT)
{
  __shared__ u16 t[64 * 66];
  __shared__ float rl[64];
  const int zl = blockIdx.y;
  const int s0 = blockIdx.x * 64;
  const int tid = threadIdx.x;
  const int r = tid >> 2, cg = (tid & 3) << 4;
  const u16* src = V + ((long)zl << 16) + (long)(s0 + r) * 64 + cg;
  v4u16 a0 = *(const v4u16*)(src);
  v4u16 a1 = *(const v4u16*)(src + 4);
  v4u16 a2 = *(const v4u16*)(src + 8);
  v4u16 a3 = *(const v4u16*)(src + 12);
  if (tid < 64) rl[tid] = 1.f / rc[(zl << 10) + s0 + tid];
  u16 tmp[16] = {(u16)a0.x, (u16)a0.y, (u16)a0.z, (u16)a0.w,
                 (u16)a1.x, (u16)a1.y, (u16)a1.z, (u16)a1.w,
                 (u16)a2.x, (u16)a2.y, (u16)a2.z, (u16)a2.w,
                 (u16)a3.x, (u16)a3.y, (u16)a3.z, (u16)a3.w};
#pragma unroll
  for (int i = 0; i < 16; i++) t[(cg + i) * 66 + r] = tmp[i];
  __syncthreads();
  const int e = tid >> 2, sg = (tid & 3) << 4;
  u16* dst = vT + ((long)zl << 16) + (long)e * 1024 + s0 + sg;
  v4u16 o;
#pragma unroll
  for (int q = 0; q < 4; q++) {
#pragma unroll
    for (int w = 0; w < 4; w++) {
      float f = bf2f(t[e * 66 + sg + q * 4 + w]) * rl[sg + q * 4 + w];
      ((u16*)&o)[w] = f2bf(f);
    }
    *(v4u16*)(dst + q * 4) = o;
  }
}

// Combine split-K bf16 partials + bias + residual, then LayerNorm. One block/row.
__global__ __launch_bounds__(256)
void ln_comb(const u16* __restrict__ p0, const u16* __restrict__ p1,
             const float* __restrict__ bias,
             const float* __restrict__ resf, const u16* __restrict__ resb,
             const float* __restrict__ gam, const float* __restrict__ bet,
             float* __restrict__ outf, u16* __restrict__ outb)
{
  long row = blockIdx.x;
  long base = (row << 10) + (threadIdx.x << 2);
  v4u16 a = *(const v4u16*)(p0 + base);
  v4u16 b = *(const v4u16*)(p1 + base);
  v4f bi = *(const v4f*)(bias + (threadIdx.x << 2));
  v4f v;
  v.x = bf2f(a.x) + bf2f(b.x) + bi.x;
  v.y = bf2f(a.y) + bf2f(b.y) + bi.y;
  v.z = bf2f(a.z) + bf2f(b.z) + bi.z;
  v.w = bf2f(a.w) + bf2f(b.w) + bi.w;
  if (resf) {
    v4f r = *(const v4f*)(resf + base);
    v.x += r.x; v.y += r.y; v.z += r.z; v.w += r.w;
  } else {
    v4u16 r = *(const v4u16*)(resb + base);
    v.x += bf2f(r.x); v.y += bf2f(r.y); v.z += bf2f(r.z); v.w += bf2f(r.w);
  }
  float s = v.x + v.y + v.z + v.w;
  float s2 = v.x * v.x + v.y * v.y + v.z * v.z + v.w * v.w;
#pragma unroll
  for (int o = 32; o > 0; o >>= 1) { s += __shfl_down(s, o); s2 += __shfl_down(s2, o); }
  __shared__ float red[8];
  int wv_ = threadIdx.x >> 6, ln = threadIdx.x & 63;
  if (ln == 0) { red[wv_] = s; red[4 + wv_] = s2; }
  __syncthreads();
  float S1 = red[0] + red[1] + red[2] + red[3];
  float S2 = red[4] + red[5] + red[6] + red[7];
  float mu = S1 * (1.f / 1024.f);
  float var = S2 * (1.f / 1024.f) - mu * mu;
  float rstd = rsqrtf(var + 1e-5f);
  v4f g4 = *(const v4f*)(gam + (threadIdx.x << 2));
  v4f b4 = *(const v4f*)(bet + (threadIdx.x << 2));
  v4f o4;
  o4.x = (v.x - mu) * rstd * g4.x + b4.x;
  o4.y = (v.y - mu) * rstd * g4.y + b4.y;
  o4.z = (v.z - mu) * rstd * g4.z + b4.z;
  o4.w = (v.w - mu) * rstd * g4.w + b4.w;
  if (outf) *(v4f*)(outf + base) = o4;
  if (outb) {
    v4u16 u;
    u.x = f2bf(o4.x); u.y = f2bf(o4.y); u.z = f2bf(o4.z); u.w = f2bf(o4.w);
    *(v4u16*)(outb + base) = u;
  }
}

// LayerNorm over 1024 cols; one block per row (fallback path).
__global__ __launch_bounds__(256)
void ln_kernel(const float* __restrict__ in, const float* __restrict__ gam,
               const float* __restrict__ bet, float* __restrict__ outf,
               u16* __restrict__ outb)
{
  long row = blockIdx.x;
  v4f v = *(const v4f*)(in + (row << 10) + (threadIdx.x << 2));
  float s = v.x + v.y + v.z + v.w;
  float s2 = v.x * v.x + v.y * v.y + v.z * v.z + v.w * v.w;
#pragma unroll
  for (int o = 32; o > 0; o >>= 1) { s += __shfl_down(s, o); s2 += __shfl_down(s2, o); }
  __shared__ float red[8];
  int wv_ = threadIdx.x >> 6, ln = threadIdx.x & 63;
  if (ln == 0) { red[wv_] = s; red[4 + wv_] = s2; }
  __syncthreads();
  float S1 = red[0] + red[1] + red[2] + red[3];
  float S2 = red[4] + red[5] + red[6] + red[7];
  float mu = S1 * (1.f / 1024.f);
  float var = S2 * (1.f / 1024.f) - mu * mu;
  float rstd = rsqrtf(var + 1e-5f);
  v4f g4 = *(const v4f*)(gam + (threadIdx.x << 2));
  v4f b4 = *(const v4f*)(bet + (threadIdx.x << 2));
  v4f o4;
  o4.x = (v.x - mu) * rstd * g4.x + b4.x;
  o4.y = (v.y - mu) * rstd * g4.y + b4.y;
  o4.z = (v.z - mu) * rstd * g4.z + b4.z;
  o4.w = (v.w - mu) * rstd * g4.w + b4.w;
  if (outf) *(v4f*)(outf + (row << 10) + (threadIdx.x << 2)) = o4;
  if (outb) {
    v4u16 u;
    u.x = f2bf(o4.x); u.y = f2bf(o4.y); u.z = f2bf(o4.z); u.w = f2bf(o4.w);
    *(v4u16*)(outb + (row << 10) + (threadIdx.x << 2)) = u;
  }
}

__global__ __launch_bounds__(256)
void cvt_bf16(const float* __restrict__ in, u16* __restrict__ out, int n4)
{
  int i = blockIdx.x * 256 + threadIdx.x;
  if (i >= n4) return;
  v4f v = ((const v4f*)in)[i];
  v4u16 u;
  u.x = f2bf(v.x); u.y = f2bf(v.y); u.z = f2bf(v.z); u.w = f2bf(v.w);
  ((v4u16*)out)[i] = u;
}

// Pack wq/wk/wv [h][d][e] -> B matrix [n = w*1024 + h*64 + e][d] bf16.
__global__ __launch_bounds__(256)
void pack_qkvw(const float* __restrict__ wq, const float* __restrict__ wk,
               const float* __restrict__ wv, u16* __restrict__ out)
{
  int i = blockIdx.x * 256 + threadIdx.x;  // 3*2^20 total
  int w = i >> 20, r = i & 1048575;
  int e = r & 63, d = (r >> 6) & 1023, h = r >> 16;
  const float* src = (w == 0) ? wq : ((w == 1) ? wk : wv);
  float v = src[(((long)h << 10) + d) * 64 + e];
  out[((((long)w << 10) + (h << 6) + e) << 10) + d] = f2bf(v);
}

// Detect whether mask is int32 (bytes at i%4!=0 all zero) or bool bytes.
__global__ void detect_mask_kernel(const unsigned char* __restrict__ m, int* __restrict__ flag)
{
  if (threadIdx.x == 0 && blockIdx.x == 0) {
    int nz = 0;
    for (int i = 0; i < 256; i++)
      if ((i & 3) != 0 && m[i] != 0) nz++;
    *flag = (nz == 0) ? 1 : 0;
  }
}

// Canonicalize mask into u8 {0,1} bytes (fallback path).
__global__ __launch_bounds__(256)
void canon_mask(const unsigned char* __restrict__ m, const int* __restrict__ flag,
                unsigned char* __restrict__ out)
{
  int i = blockIdx.x * 256 + threadIdx.x;
  uchar4 o;
  if (*flag) {
    const int* mi = (const int*)m;
    o.x = mi[i * 4 + 0] != 0; o.y = mi[i * 4 + 1] != 0;
    o.z = mi[i * 4 + 2] != 0; o.w = mi[i * 4 + 3] != 0;
  } else {
    o = ((const uchar4*)m)[i];
  }
  ((uchar4*)out)[i] = o;
}

// Bit-pack mask: out word g covers entries [32g, 32g+32), bit = entry&31.
__global__ __launch_bounds__(256)
void canon_pack(const unsigned char* __restrict__ m, const int* __restrict__ flag,
                unsigned int* __restrict__ out)
{
  int g = blockIdx.x * 256 + threadIdx.x;  // 262144 total
  unsigned int bits = 0;
  if (*flag) {
    const int* mi = (const int*)m + (long)g * 32;
#pragma unroll
    for (int i = 0; i < 32; i++) bits |= (mi[i] != 0 ? 1u : 0u) << i;
  } else {
    const unsigned char* mb = m + (long)g * 32;
#pragma unroll
    for (int i = 0; i < 32; i++) bits |= (mb[i] != 0 ? 1u : 0u) << i;
  }
  out[g] = bits;
}

extern "C" void kernel_launch(void* const* d_in, const int* in_sizes, int n_in,
                              void* d_out, int out_size, void* d_ws, size_t ws_size,
                              hipStream_t stream)
{
  const float* x     = (const float*)d_in[0];
  const unsigned char* mask = (const unsigned char*)d_in[1];
  const float* wq    = (const float*)d_in[2];
  const float* wk    = (const float*)d_in[3];
  const float* wv    = (const float*)d_in[4];
  const float* fc_w  = (const float*)d_in[5];
  const float* fc_b  = (const float*)d_in[6];
  const float* w1    = (const float*)d_in[7];
  const float* b1    = (const float*)d_in[8];
  const float* w2    = (const float*)d_in[9];
  const float* b2    = (const float*)d_in[10];
  const float* ln1_g = (const float*)d_in[11];
  const float* ln1_b = (const float*)d_in[12];
  const float* ln2_g = (const float*)d_in[13];
  const float* ln2_b = (const float*)d_in[14];
  (void)in_sizes; (void)n_in; (void)out_size;

  // ---- workspace map (aliased lifetimes) ----
  const size_t MB = 1ull << 20;
  char* ws = (char*)d_ws;
  int*   mflag = (int*)ws;                  // 4 B
  float* rc    = (float*)(ws + 65536);      // 512 KB
  unsigned char* Mpk = (unsigned char*)(ws + 1 * MB);  // 1 MB bit-packed mask
  u16*   bqkv  = (u16*)(ws + 2 * MB);       // 6 MB
  u16*   fcb   = (u16*)(ws + 8 * MB);       // 2 MB
  u16*   w1b   = (u16*)(ws + 10 * MB);      // 8 MB
  u16*   w2b   = (u16*)(ws + 18 * MB);      // 8 MB
  u16*   xb    = (u16*)(ws + 26 * MB);      // 16 MB -> x1b alias
  u16*   x1b   = xb;
  u16*   Qb    = (u16*)(ws + 42 * MB);      // 16 MB
  u16*   Kb    = (u16*)(ws + 58 * MB);      // 16 MB
  u16*   Vb    = (u16*)(ws + 74 * MB);      // 16 MB ([z,s,e])
  u16*   vT    = (u16*)(ws + 90 * MB);      // 16 MB ([z,e,s], scaled)
  u16*   oc    = (u16*)(ws + 106 * MB);     // 16 MB
  u16*   h1    = (u16*)(ws + 42 * MB);      // 64 MB alias Qb..vT (post-attention)
  float* r1    = (float*)(ws + 122 * MB);   // 32 MB (fallback path only)
  unsigned char* Mb = (unsigned char*)(ws + 122 * MB);  // 8 MB (fallback attn)
  u16*   E     = (u16*)(ws + 122 * MB);     // 2*CZ MB (aliases r1)
  u16*   p0    = (u16*)(ws + 122 * MB);     // 16 MB bf16 split-K partial (post-attn)
  u16*   p1    = (u16*)(ws + 138 * MB);     // 16 MB bf16 split-K partial

  // chunk tier by workspace: peak = 122 MB + 2*CZ MB (min split-K tier = 154 MB)
  int CZ = 0;
  if      (ws_size >= 378 * MB) CZ = 128;
  else if (ws_size >= 250 * MB) CZ = 64;
  else if (ws_size >= 186 * MB) CZ = 32;
  else if (ws_size >= 154 * MB) CZ = 16;

  detect_mask_kernel<<<1, 64, 0, stream>>>(mask, mflag);
  if (CZ > 0) canon_pack<<<1024, 256, 0, stream>>>(mask, mflag, (unsigned int*)Mpk);
  else        canon_mask<<<8192, 256, 0, stream>>>(mask, mflag, Mb);

  cvt_bf16<<<8192, 256, 0, stream>>>(x, xb, 2097152);
  pack_qkvw<<<12288, 256, 0, stream>>>(wq, wk, wv, bqkv);
  cvt_bf16<<<1024, 256, 0, stream>>>(fc_w, fcb, 262144);
  cvt_bf16<<<4096, 256, 0, stream>>>(w1, w1b, 1048576);
  cvt_bf16<<<4096, 256, 0, stream>>>(w2, w2b, 1048576);

  // QKV projections: [8192 x 1024] x [3072 x 1024]^T ; tiles 24x64
  {
    EpArgs ep = {};
    ep.q = Qb; ep.k = Kb; ep.v = Vb;
    gemm_nt<128, 128, 4, 4, MODE_QKV><<<dim3(24 * 64, 1), 256, 0, stream>>>(
        xb, 1024, 0, bqkv, 1024, 0, 1024, 3072, 24, 64, ep);
  }

  hipMemsetAsync(rc, 0, 128 * 1024 * 4, stream);
  if (CZ > 0) {
    for (int z0 = 0; z0 < 128; z0 += CZ) {
      attn_score<<<dim3(8, 8, CZ), 256, 0, stream>>>(
          Qb + (long)z0 * 65536, Kb + (long)z0 * 65536, Mpk,
          rc + (long)z0 * 1024, E, z0);
      transpose_scale<<<dim3(16, CZ), 256, 0, stream>>>(
          Vb + (long)z0 * 65536, rc + (long)z0 * 1024, vT + (long)z0 * 65536);
      EpArgs ep = {};
      ep.outb = oc; ep.z0 = z0;
      gemm_nt<128, 64, 4, 2, MODE_PV><<<dim3(8, CZ), 256, 0, stream>>>(
          E, 1024, 1048576, vT + (long)z0 * 65536, 1024, 65536,
          1024, 64, 1, 8, ep);
    }
  } else {
    attn_colsum<<<dim3(8, 128), 256, 0, stream>>>(Qb, Kb, Mb, rc);
    transpose_scale<<<dim3(16, 128), 256, 0, stream>>>(Vb, rc, vT);
    attn_pv<<<dim3(8, 128), 256, 0, stream>>>(Qb, Kb, vT, Mb, oc);
  }

  if (CZ > 0) {
    // proj split-K: K=1024 -> 2x512 slices; bf16 partials p0/p1; combine in LN1
    {
      EpArgs ep = {};
      ep.outb = p0; ep.outb2 = p1;
      gemm_nt<128, 128, 4, 4, MODE_PARTIAL><<<dim3(8 * 64, 2), 256, 0, stream>>>(
          oc, 1024, 512, fcb, 1024, 512, 512, 1024, 8, 64, ep);
    }
    ln_comb<<<8192, 256, 0, stream>>>(p0, p1, fc_b, x, (const u16*)nullptr,
                                      ln1_g, ln1_b, (float*)nullptr, x1b);
    // h1 = relu(x1 @ w1^T + b1) bf16
    {
      EpArgs ep = {};
      ep.bias = b1; ep.outb = h1;
      gemm_nt<128, 128, 4, 4, MODE_BIAS_RELU><<<dim3(32 * 64, 1), 256, 0, stream>>>(
          x1b, 1024, 0, w1b, 1024, 0, 1024, 4096, 32, 64, ep);
    }
    // MLP2 split-K: K=4096 -> 2x2048 slices; combine + residual + LN2 -> d_out
    {
      EpArgs ep = {};
      ep.outb = p0; ep.outb2 = p1;
      gemm_nt<128, 128, 4, 4, MODE_PARTIAL><<<dim3(8 * 64, 2), 256, 0, stream>>>(
          h1, 4096, 2048, w2b, 4096, 2048, 2048, 1024, 8, 64, ep);
    }
    ln_comb<<<8192, 256, 0, stream>>>(p0, p1, b2, (const float*)nullptr, x1b,
                                      ln2_g, ln2_b, (float*)d_out, (u16*)nullptr);
  } else {
    {
      EpArgs ep = {};
      ep.bias = fc_b; ep.res = x; ep.outf = r1;
      gemm_nt<128, 128, 4, 4, MODE_BIAS_RES><<<dim3(8 * 64, 1), 256, 0, stream>>>(
          oc, 1024, 0, fcb, 1024, 0, 1024, 1024, 8, 64, ep);
    }
    ln_kernel<<<8192, 256, 0, stream>>>(r1, ln1_g, ln1_b, (float*)nullptr, x1b);
    {
      EpArgs ep = {};
      ep.bias = b1; ep.outb = h1;
      gemm_nt<128, 128, 4, 4, MODE_BIAS_RELU><<<dim3(32 * 64, 1), 256, 0, stream>>>(
          x1b, 1024, 0, w1b, 1024, 0, 1024, 4096, 32, 64, ep);
    }
    {
      EpArgs ep = {};
      ep.bias = b2; ep.res_bf = x1b; ep.outf = r1;
      gemm_nt<128, 128, 4, 4, MODE_BIAS_RES><<<dim3(8 * 64, 1), 256, 0, stream>>>(
          h1, 4096, 0, w2b, 4096, 0, 4096, 1024, 8, 64, ep);
    }
    ln_kernel<<<8192, 256, 0, stream>>>(r1, ln2_g, ln2_b, (float*)d_out, (u16*)nullptr);
  }
}

// Round 7
// 607.173 us; speedup vs baseline: 2.2175x; 1.0516x over previous
//
#include <hip/hip_runtime.h>
#include <stdint.h>

#define DEV static __device__ __forceinline__

typedef unsigned short u16;
typedef __attribute__((ext_vector_type(8))) short v8s;    // 8 x bf16 MFMA operand
typedef __attribute__((ext_vector_type(4))) float v4f;
typedef __attribute__((ext_vector_type(4))) unsigned short v4u16;

DEV u16 f2bf(float f) {
  union { float f; unsigned u; } c; c.f = f;
  unsigned r = c.u + 0x7FFFu + ((c.u >> 16) & 1u);
  return (u16)(r >> 16);
}
DEV float bf2f(u16 h) {
  union { unsigned u; float f; } c; c.u = ((unsigned)h) << 16;
  return c.f;
}
DEV unsigned char f2fp8(float f) {  // OCP e4m3, RNE, saturating
  return (unsigned char)(__builtin_amdgcn_cvt_pk_fp8_f32(f, 0.f, 0, false) & 0xff);
}
DEV float fp82f(unsigned char b) {
  return __builtin_amdgcn_cvt_f32_fp8((int)b, 0);
}

// async global->LDS, 16B per lane; LDS dest = wave-uniform base + lane*16.
DEV void gload16(const u16* g, u16* l) {
  __builtin_amdgcn_global_load_lds(
      (const __attribute__((address_space(1))) unsigned int*)g,
      (__attribute__((address_space(3))) unsigned int*)l, 16, 0, 0);
}
DEV void gload16b(const unsigned char* g, unsigned char* l) {
  __builtin_amdgcn_global_load_lds(
      (const __attribute__((address_space(1))) unsigned int*)g,
      (__attribute__((address_space(3))) unsigned int*)l, 16, 0, 0);
}

enum { MODE_QKV = 0, MODE_BIAS_RES = 3, MODE_BIAS_RELU = 4, MODE_PARTIAL = 5 };

struct EpArgs {
  const float* bias;          // BIAS_*
  const float* res;           // BIAS_RES fp32 residual (or null)
  const u16* res_bf;          // BIAS_RES bf16 residual (used if res==null)
  float* outf;                // BIAS_RES
  u16* outb;                  // BIAS_RELU/PARTIAL slice 0
  u16* outb2;                 // PARTIAL slice 1
  u16* q; u16* k; u16* v;     // QKV scatter (all [z,s,e])
  int z0;
};

// NT GEMM: C[m][n] = sum_k A[m][k]*B[n][k]. BK=32, 256 thr = 4 waves (2x2).
// Tiles flattened into grid.x, XCD-aware swizzle (nby multiple of 8). z = blockIdx.y.
template <int BM, int BN, int FM, int FN, int MODE>
__global__ __launch_bounds__(256, 2)
void gemm_nt(const u16* __restrict__ A, int lda, long sA,
             const u16* __restrict__ B, int ldb, long sB,
             int K, int N, int nbx, int nby, EpArgs ep)
{
  __shared__ u16 As[BM * 32];
  __shared__ u16 Bs[BN * 32];

  const int tid  = threadIdx.x;
  const int lane = tid & 63;
  const int wave = tid >> 6;
  const int wm = (wave >> 1) * (FM * 16);
  const int wn = (wave & 1) * (FN * 16);

  const int id = blockIdx.x;
  const int nby8 = nby >> 3;
  const int c8 = id & 7, jj = id >> 3;
  const int tm = ((jj % nby8) * 8 + c8) * BM;
  const int tn = (jj / nby8) * BN;
  const int z  = blockIdx.y;

  const u16* Az = A + (long)z * sA;
  const u16* Bz = B + (long)z * sB;

  v4f acc[FM][FN];
  const v4f zero4 = {0.f, 0.f, 0.f, 0.f};
#pragma unroll
  for (int i = 0; i < FM; i++)
#pragma unroll
    for (int j = 0; j < FN; j++) acc[i][j] = zero4;

  for (int kt = 0; kt < K; kt += 32) {
#pragma unroll
    for (int c = 0; c < BM * 4; c += 256) {
      int cc = c + tid;
      int row = cc >> 2, kk = (cc & 3) * 8;
      gload16(Az + (long)(tm + row) * lda + kt + kk, &As[cc * 8]);
    }
#pragma unroll
    for (int c = 0; c < BN * 4; c += 256) {
      int cc = c + tid;
      int row = cc >> 2, kk = (cc & 3) * 8;
      gload16(Bz + (long)(tn + row) * ldb + kt + kk, &Bs[cc * 8]);
    }
    __syncthreads();

    v8s af[FM], bfr[FN];
#pragma unroll
    for (int i = 0; i < FM; i++)
      af[i] = *(const v8s*)&As[(wm + i * 16 + (lane & 15)) * 32 + (lane >> 4) * 8];
#pragma unroll
    for (int j = 0; j < FN; j++)
      bfr[j] = *(const v8s*)&Bs[(wn + j * 16 + (lane & 15)) * 32 + (lane >> 4) * 8];
#pragma unroll
    for (int i = 0; i < FM; i++)
#pragma unroll
      for (int j = 0; j < FN; j++)
        acc[i][j] = __builtin_amdgcn_mfma_f32_16x16x32_bf16(af[i], bfr[j], acc[i][j], 0, 0, 0);
    __syncthreads();
  }

  bool res_is_f32 = false;
  if constexpr (MODE == MODE_BIAS_RES) res_is_f32 = (ep.res != nullptr);
  u16* pdst = nullptr;
  if constexpr (MODE == MODE_PARTIAL) pdst = z ? ep.outb2 : ep.outb;

  // C/D layout: col = lane&15, row = (lane>>4)*4 + r
#pragma unroll
  for (int i = 0; i < FM; i++) {
    int mbase = tm + wm + i * 16 + ((lane >> 4) << 2);
#pragma unroll
    for (int j = 0; j < FN; j++) {
      int n = tn + wn + j * 16 + (lane & 15);
#pragma unroll
      for (int r = 0; r < 4; r++) {
        float val = acc[i][j][r];
        int m = mbase + r;
        if constexpr (MODE == MODE_QKV) {
          int b = m >> 10, s = m & 1023;
          int w = n >> 10, rr = n & 1023, h = rr >> 6, e = rr & 63;
          long idx = (((long)(b * 16 + h) << 10) + s) * 64 + e;  // [z,s,e]
          u16* dst = (w == 0) ? ep.q : (w == 1) ? ep.k : ep.v;
          dst[idx] = f2bf(val);
        } else if constexpr (MODE == MODE_BIAS_RES) {
          long idx = (long)m * N + n;
          float rres = res_is_f32 ? ep.res[idx] : bf2f(ep.res_bf[idx]);
          ep.outf[idx] = val + ep.bias[n] + rres;
        } else if constexpr (MODE == MODE_BIAS_RELU) {
          float v2 = val + ep.bias[n];
          ep.outb[(long)m * N + n] = f2bf(fmaxf(v2, 0.f));
        } else if constexpr (MODE == MODE_PARTIAL) {
          pdst[(long)m * N + n] = f2bf(val);
        }
      }
    }
  }
}

// ---- attention pass 1: S = Q K^T, E = exp(masked/8) quantized to fp8 e4m3,
// colsum (of the fp8-rounded values) atomics, coalesced fp8 E store.
// One 128x128 tile per block; grid (8 ktile, 8 qtile, CZ).
__global__ __launch_bounds__(256, 4)
void attn_score(const u16* __restrict__ Q, const u16* __restrict__ Kb,
                const unsigned char* __restrict__ Mpk, float* __restrict__ rc,
                unsigned char* __restrict__ E8, int z0)
{
  __shared__ u16 sh[17408];           // Q/K staging (32 KB), reused as P (stride 136 u16)
  __shared__ unsigned char Ms[2048];  // mask bits for this 128x128 tile
  const int tid = threadIdx.x, lane = tid & 63, wave = tid >> 6;
  const int wm = (wave >> 1) * 64, wn = (wave & 1) * 64;
  const int zl = blockIdx.z, q0 = blockIdx.y * 128, n0 = blockIdx.x * 128;
  const int b = (z0 + zl) >> 4;
  const u16* Qz = Q + ((long)zl << 16);
  const u16* Kz = Kb + ((long)zl << 16);
  u16* Qs = sh;           // [2 slabs][128][32]
  u16* Ks = sh + 8192;
  u16* Ps = sh;           // reuse after MFMA, row stride 136 u16 (bf16 of e4m3 values)

#pragma unroll
  for (int c = 0; c < 4; c++) {
    int cc = c * 256 + tid;
    int s = cc >> 9, rem = cc & 511, row = rem >> 2, k0 = (rem & 3) * 8;
    gload16(Qz + (long)(q0 + row) * 64 + s * 32 + k0, &Qs[cc * 8]);
  }
#pragma unroll
  for (int c = 0; c < 4; c++) {
    int cc = c * 256 + tid;
    int s = cc >> 9, rem = cc & 511, row = rem >> 2, k0 = (rem & 3) * 8;
    gload16(Kz + (long)(n0 + row) * 64 + s * 32 + k0, &Ks[cc * 8]);
  }
  if (tid < 128)
    ((uint4*)Ms)[tid] =
        *(const uint4*)(Mpk + ((long)b << 17) + (long)(q0 + tid) * 128 + (n0 >> 3));
  __syncthreads();

  v4f sacc[4][4];
  const v4f zero4 = {0.f, 0.f, 0.f, 0.f};
#pragma unroll
  for (int i = 0; i < 4; i++)
#pragma unroll
    for (int j = 0; j < 4; j++) sacc[i][j] = zero4;
#pragma unroll
  for (int s = 0; s < 2; s++) {
    v8s af[4], bf[4];
#pragma unroll
    for (int i = 0; i < 4; i++)
      af[i] = *(const v8s*)&Qs[s * 4096 + (wm + i * 16 + (lane & 15)) * 32 + (lane >> 4) * 8];
#pragma unroll
    for (int j = 0; j < 4; j++)
      bf[j] = *(const v8s*)&Ks[s * 4096 + (wn + j * 16 + (lane & 15)) * 32 + (lane >> 4) * 8];
#pragma unroll
    for (int i = 0; i < 4; i++)
#pragma unroll
      for (int j = 0; j < 4; j++)
        sacc[i][j] = __builtin_amdgcn_mfma_f32_16x16x32_bf16(af[i], bf[j], sacc[i][j], 0, 0, 0);
  }
  __syncthreads();  // all Qs/Ks reads done before Ps overwrite

#pragma unroll
  for (int j = 0; j < 4; j++) {
    int col = wn + j * 16 + (lane & 15);
    float csum = 0.f;
#pragma unroll
    for (int i = 0; i < 4; i++) {
      int mlb = wm + i * 16 + ((lane >> 4) << 2);
#pragma unroll
      for (int r = 0; r < 4; r++) {
        int ml = mlb + r;
        bool mk = (Ms[ml * 16 + (col >> 3)] >> (col & 7)) & 1;
        float ev = mk ? __expf(sacc[i][j][r] * 0.125f) : 0.f;
        float evq = fp82f(f2fp8(ev));   // e4m3-rounded value PV will use
        Ps[ml * 136 + col] = f2bf(evq); // exact (e4m3 subset of bf16)
        csum += evq;
      }
    }
    csum += __shfl_xor(csum, 16);
    csum += __shfl_xor(csum, 32);
    if (lane < 16) atomicAdd(&rc[(zl << 10) + n0 + col], csum);
  }
  __syncthreads();

  // coalesced fp8 E store: 8 B/lane (8 values), row-major
  unsigned char* Ez = E8 + ((long)zl << 20);
#pragma unroll
  for (int it = 0; it < 8; it++) {
    int idx = it * 256 + tid;
    int row = idx >> 4, c8 = (idx & 15) * 8;
    v4u16 a = *(const v4u16*)&Ps[row * 136 + c8];
    v4u16 bb = *(const v4u16*)&Ps[row * 136 + c8 + 4];
    int w0 = __builtin_amdgcn_cvt_pk_fp8_f32(bf2f(a.x), bf2f(a.y), 0, false);
    w0 = __builtin_amdgcn_cvt_pk_fp8_f32(bf2f(a.z), bf2f(a.w), w0, true);
    int w1 = __builtin_amdgcn_cvt_pk_fp8_f32(bf2f(bb.x), bf2f(bb.y), 0, false);
    w1 = __builtin_amdgcn_cvt_pk_fp8_f32(bf2f(bb.z), bf2f(bb.w), w1, true);
    uint2 o; o.x = (unsigned)w0; o.y = (unsigned)w1;
    *(uint2*)(Ez + (long)(q0 + row) * 1024 + n0 + c8) = o;
  }
}

// ---- attention pass 2: O = E8 * V'^T, fp8 MFMA NT GEMM. grid (8 qtiles, CZ).
// A = E8 [zl][q][s] (lda 1024 B), B = vT8 [zl][e][s] (ldb 1024 B). BM=128 BN=64 BK=32.
__global__ __launch_bounds__(256, 2)
void attn_pv_fp8(const unsigned char* __restrict__ E8,
                 const unsigned char* __restrict__ vT8,
                 u16* __restrict__ oc, int z0)
{
  __shared__ unsigned char As[128 * 32];  // 4 KB
  __shared__ unsigned char Bs[64 * 32];   // 2 KB
  const int tid = threadIdx.x, lane = tid & 63, wave = tid >> 6;
  const int wm = (wave >> 1) * 64;   // FM=4
  const int wn = (wave & 1) * 32;    // FN=2
  const int zl = blockIdx.y, q0 = blockIdx.x * 128;
  const int zg = z0 + zl, b = zg >> 4, h = zg & 15;
  const unsigned char* Ez = E8 + ((long)zl << 20);
  const unsigned char* Vz = vT8 + ((long)zl << 16);

  v4f acc[4][2];
  const v4f zero4 = {0.f, 0.f, 0.f, 0.f};
#pragma unroll
  for (int i = 0; i < 4; i++)
#pragma unroll
    for (int j = 0; j < 2; j++) acc[i][j] = zero4;

  for (int kt = 0; kt < 1024; kt += 32) {
    {
      int row = tid >> 1, off = (tid & 1) * 16;
      gload16b(Ez + (long)(q0 + row) * 1024 + kt + off, &As[row * 32 + off]);
    }
    if (tid < 128) {
      int row = tid >> 1, off = (tid & 1) * 16;
      gload16b(Vz + (long)row * 1024 + kt + off, &Bs[row * 32 + off]);
    }
    __syncthreads();

    long bfr[2];
#pragma unroll
    for (int j = 0; j < 2; j++)
      bfr[j] = *(const long*)&Bs[(wn + j * 16 + (lane & 15)) * 32 + (lane >> 4) * 8];
#pragma unroll
    for (int i = 0; i < 4; i++) {
      long af = *(const long*)&As[(wm + i * 16 + (lane & 15)) * 32 + (lane >> 4) * 8];
#pragma unroll
      for (int j = 0; j < 2; j++)
        acc[i][j] = __builtin_amdgcn_mfma_f32_16x16x32_fp8_fp8(af, bfr[j], acc[i][j], 0, 0, 0);
    }
    __syncthreads();
  }

  // write O (undo the 512x V' scale): oc[(b*1024+q)*1024 + h*64 + v]
#pragma unroll
  for (int i = 0; i < 4; i++) {
    int mbase = q0 + wm + i * 16 + ((lane >> 4) << 2);
#pragma unroll
    for (int j = 0; j < 2; j++) {
      int n = wn + j * 16 + (lane & 15);
#pragma unroll
      for (int r = 0; r < 4; r++) {
        int m = mbase + r;
        oc[((long)(b * 1024 + m) << 10) + h * 64 + n] = f2bf(acc[i][j][r] * (1.f / 512.f));
      }
    }
  }
}

// ---- fallback two-pass attention (no E), proven in R4 ----
__global__ __launch_bounds__(256, 2)
void attn_colsum(const u16* __restrict__ Q, const u16* __restrict__ Kb,
                 const unsigned char* __restrict__ Mb, float* __restrict__ rc)
{
  __shared__ u16 Qs[2 * 128 * 32];
  __shared__ u16 Ks[2 * 128 * 32];
  const int tid = threadIdx.x, lane = tid & 63, wave = tid >> 6;
  const int wm = (wave >> 1) * 64, wn = (wave & 1) * 64;
  const int z = blockIdx.y, q0 = blockIdx.x * 128, b = z >> 4;
  const u16* Qz = Q + ((long)z << 16);
  const u16* Kz = Kb + ((long)z << 16);
  const unsigned char* Mz = Mb + ((long)b << 20);

#pragma unroll
  for (int c = 0; c < 4; c++) {
    int cc = c * 256 + tid;
    int s = cc >> 9, rem = cc & 511, row = rem >> 2, k0 = (rem & 3) * 8;
    gload16(Qz + (long)(q0 + row) * 64 + s * 32 + k0, &Qs[cc * 8]);
  }

  for (int nt = 0; nt < 8; nt++) {
    int n0 = nt * 128;
#pragma unroll
    for (int c = 0; c < 4; c++) {
      int cc = c * 256 + tid;
      int s = cc >> 9, rem = cc & 511, row = rem >> 2, k0 = (rem & 3) * 8;
      gload16(Kz + (long)(n0 + row) * 64 + s * 32 + k0, &Ks[cc * 8]);
    }
    __syncthreads();

    v4f sacc[4][4];
    const v4f zero4 = {0.f, 0.f, 0.f, 0.f};
#pragma unroll
    for (int i = 0; i < 4; i++)
#pragma unroll
      for (int j = 0; j < 4; j++) sacc[i][j] = zero4;
#pragma unroll
    for (int s = 0; s < 2; s++) {
      v8s af[4], bf[4];
#pragma unroll
      for (int i = 0; i < 4; i++)
        af[i] = *(const v8s*)&Qs[s * 4096 + (wm + i * 16 + (lane & 15)) * 32 + (lane >> 4) * 8];
#pragma unroll
      for (int j = 0; j < 4; j++)
        bf[j] = *(const v8s*)&Ks[s * 4096 + (wn + j * 16 + (lane & 15)) * 32 + (lane >> 4) * 8];
#pragma unroll
      for (int i = 0; i < 4; i++)
#pragma unroll
        for (int j = 0; j < 4; j++)
          sacc[i][j] = __builtin_amdgcn_mfma_f32_16x16x32_bf16(af[i], bf[j], sacc[i][j], 0, 0, 0);
    }

#pragma unroll
    for (int j = 0; j < 4; j++) {
      int n = n0 + wn + j * 16 + (lane & 15);
      float csum = 0.f;
#pragma unroll
      for (int i = 0; i < 4; i++) {
        int mbase = q0 + wm + i * 16 + ((lane >> 4) << 2);
#pragma unroll
        for (int r = 0; r < 4; r++) {
          int m = mbase + r;
          bool mk = Mz[(long)m * 1024 + n] != 0;
          float sv = mk ? sacc[i][j][r] : -1000.0f;
          csum += bf2f(f2bf(__expf(sv * 0.125f)));
        }
      }
      csum += __shfl_xor(csum, 16);
      csum += __shfl_xor(csum, 32);
      if (lane < 16) atomicAdd(&rc[(z << 10) + n], csum);
    }
    __syncthreads();
  }
}

__global__ __launch_bounds__(256, 2)
void attn_pv(const u16* __restrict__ Q, const u16* __restrict__ Kb,
             const u16* __restrict__ vT, const unsigned char* __restrict__ Mb,
             u16* __restrict__ oc)
{
  __shared__ u16 Ks[2 * 128 * 32];
  __shared__ u16 Vs[4 * 64 * 32];
  __shared__ u16 Ps[4 * 128 * 32];
  const int tid = threadIdx.x, lane = tid & 63, wave = tid >> 6;
  const int wm = (wave >> 1) * 64;
  const int wn = (wave & 1) * 64;
  const int wnv = (wave & 1) * 32;
  const int z = blockIdx.y, q0 = blockIdx.x * 128, b = z >> 4, h = z & 15;
  const u16* Qz = Q + ((long)z << 16);
  const u16* Kz = Kb + ((long)z << 16);
  const u16* Vz = vT + ((long)z << 16);
  const unsigned char* Mz = Mb + ((long)b << 20);

#pragma unroll
  for (int c = 0; c < 4; c++) {
    int cc = c * 256 + tid;
    int s = cc >> 9, rem = cc & 511, row = rem >> 2, k0 = (rem & 3) * 8;
    gload16(Qz + (long)(q0 + row) * 64 + s * 32 + k0, &Ks[cc * 8]);
  }
  __syncthreads();
  v8s qf[4][2];
#pragma unroll
  for (int i = 0; i < 4; i++)
#pragma unroll
    for (int s = 0; s < 2; s++)
      qf[i][s] = *(const v8s*)&Ks[s * 4096 + (wm + i * 16 + (lane & 15)) * 32 + (lane >> 4) * 8];
  __syncthreads();

  v4f oacc[4][2];
  const v4f zero4 = {0.f, 0.f, 0.f, 0.f};
#pragma unroll
  for (int i = 0; i < 4; i++)
#pragma unroll
    for (int j = 0; j < 2; j++) oacc[i][j] = zero4;

  for (int nt = 0; nt < 8; nt++) {
    int n0 = nt * 128;
#pragma unroll
    for (int c = 0; c < 4; c++) {
      int cc = c * 256 + tid;
      int s = cc >> 9, rem = cc & 511, row = rem >> 2, k0 = (rem & 3) * 8;
      gload16(Kz + (long)(n0 + row) * 64 + s * 32 + k0, &Ks[cc * 8]);
    }
#pragma unroll
    for (int c = 0; c < 4; c++) {
      int cc = c * 256 + tid;
      int s = cc >> 8, rem = cc & 255, v = rem >> 2, k0 = (rem & 3) * 8;
      gload16(Vz + (long)v * 1024 + n0 + s * 32 + k0, &Vs[cc * 8]);
    }
    __syncthreads();

    v4f sacc[4][4];
#pragma unroll
    for (int i = 0; i < 4; i++)
#pragma unroll
      for (int j = 0; j < 4; j++) sacc[i][j] = zero4;
#pragma unroll
    for (int s = 0; s < 2; s++) {
      v8s bf[4];
#pragma unroll
      for (int j = 0; j < 4; j++)
        bf[j] = *(const v8s*)&Ks[s * 4096 + (wn + j * 16 + (lane & 15)) * 32 + (lane >> 4) * 8];
#pragma unroll
      for (int i = 0; i < 4; i++)
#pragma unroll
        for (int j = 0; j < 4; j++)
          sacc[i][j] = __builtin_amdgcn_mfma_f32_16x16x32_bf16(qf[i][s], bf[j], sacc[i][j], 0, 0, 0);
    }

#pragma unroll
    for (int i = 0; i < 4; i++) {
      int mlb = wm + i * 16 + ((lane >> 4) << 2);
#pragma unroll
      for (int j = 0; j < 4; j++) {
        int col = wn + j * 16 + (lane & 15);
        int gn = n0 + col;
#pragma unroll
        for (int r = 0; r < 4; r++) {
          int ml = mlb + r;
          bool mk = Mz[(long)(q0 + ml) * 1024 + gn] != 0;
          float sv = mk ? sacc[i][j][r] : -1000.0f;
          Ps[(col >> 5) * 4096 + ml * 32 + (col & 31)] = f2bf(__expf(sv * 0.125f));
        }
      }
    }
    __syncthreads();

#pragma unroll
    for (int s = 0; s < 4; s++) {
      v8s vf[2];
#pragma unroll
      for (int j = 0; j < 2; j++)
        vf[j] = *(const v8s*)&Vs[s * 2048 + (wnv + j * 16 + (lane & 15)) * 32 + (lane >> 4) * 8];
#pragma unroll
      for (int i = 0; i < 4; i++) {
        v8s pf = *(const v8s*)&Ps[s * 4096 + (wm + i * 16 + (lane & 15)) * 32 + (lane >> 4) * 8];
#pragma unroll
        for (int j = 0; j < 2; j++)
          oacc[i][j] = __builtin_amdgcn_mfma_f32_16x16x32_bf16(pf, vf[j], oacc[i][j], 0, 0, 0);
      }
    }
    __syncthreads();
  }

#pragma unroll
  for (int i = 0; i < 4; i++) {
    int mbase = q0 + wm + i * 16 + ((lane >> 4) << 2);
#pragma unroll
    for (int j = 0; j < 2; j++) {
      int n = wnv + j * 16 + (lane & 15);
#pragma unroll
      for (int r = 0; r < 4; r++) {
        int m = mbase + r;
        oc[((long)(b * 1024 + m) << 10) + h * 64 + n] = f2bf(oacc[i][j][r]);
      }
    }
  }
}

// Transpose V [z,s,e] -> vT [z,e,s] bf16, scaling column s by 1/colsum(s). (fallback)
__global__ __launch_bounds__(256)
void transpose_scale(const u16* __restrict__ V, const float* __restrict__ rc,
                     u16* __restrict__ vT)
{
  __shared__ u16 t[64 * 66];
  __shared__ float rl[64];
  const int zl = blockIdx.y;
  const int s0 = blockIdx.x * 64;
  const int tid = threadIdx.x;
  const int r = tid >> 2, cg = (tid & 3) << 4;
  const u16* src = V + ((long)zl << 16) + (long)(s0 + r) * 64 + cg;
  v4u16 a0 = *(const v4u16*)(src);
  v4u16 a1 = *(const v4u16*)(src + 4);
  v4u16 a2 = *(const v4u16*)(src + 8);
  v4u16 a3 = *(const v4u16*)(src + 12);
  if (tid < 64) rl[tid] = 1.f / rc[(zl << 10) + s0 + tid];
  u16 tmp[16] = {(u16)a0.x, (u16)a0.y, (u16)a0.z, (u16)a0.w,
                 (u16)a1.x, (u16)a1.y, (u16)a1.z, (u16)a1.w,
                 (u16)a2.x, (u16)a2.y, (u16)a2.z, (u16)a2.w,
                 (u16)a3.x, (u16)a3.y, (u16)a3.z, (u16)a3.w};
#pragma unroll
  for (int i = 0; i < 16; i++) t[(cg + i) * 66 + r] = tmp[i];
  __syncthreads();
  const int e = tid >> 2, sg = (tid & 3) << 4;
  u16* dst = vT + ((long)zl << 16) + (long)e * 1024 + s0 + sg;
  v4u16 o;
#pragma unroll
  for (int q = 0; q < 4; q++) {
#pragma unroll
    for (int w = 0; w < 4; w++) {
      float f = bf2f(t[e * 66 + sg + q * 4 + w]) * rl[sg + q * 4 + w];
      ((u16*)&o)[w] = f2bf(f);
    }
    *(v4u16*)(dst + q * 4) = o;
  }
}

// Transpose V [z,s,e] -> vT8 [z,e,s] fp8 e4m3, scaled by 512/colsum(s). (main path)
__global__ __launch_bounds__(256)
void transpose_scale_fp8(const u16* __restrict__ V, const float* __restrict__ rc,
                         unsigned char* __restrict__ vT8)
{
  __shared__ u16 t[64 * 66];
  __shared__ float rl[64];
  const int zl = blockIdx.y;
  const int s0 = blockIdx.x * 64;
  const int tid = threadIdx.x;
  const int r = tid >> 2, cg = (tid & 3) << 4;
  const u16* src = V + ((long)zl << 16) + (long)(s0 + r) * 64 + cg;
  v4u16 a0 = *(const v4u16*)(src);
  v4u16 a1 = *(const v4u16*)(src + 4);
  v4u16 a2 = *(const v4u16*)(src + 8);
  v4u16 a3 = *(const v4u16*)(src + 12);
  if (tid < 64) rl[tid] = 512.f / rc[(zl << 10) + s0 + tid];
  u16 tmp[16] = {(u16)a0.x, (u16)a0.y, (u16)a0.z, (u16)a0.w,
                 (u16)a1.x, (u16)a1.y, (u16)a1.z, (u16)a1.w,
                 (u16)a2.x, (u16)a2.y, (u16)a2.z, (u16)a2.w,
                 (u16)a3.x, (u16)a3.y, (u16)a3.z, (u16)a3.w};
#pragma unroll
  for (int i = 0; i < 16; i++) t[(cg + i) * 66 + r] = tmp[i];
  __syncthreads();
  const int e = tid >> 2, sg = (tid & 3) << 4;
  unsigned char* dst = vT8 + ((long)zl << 16) + (long)e * 1024 + s0 + sg;
#pragma unroll
  for (int q = 0; q < 4; q++) {
    float f0 = bf2f(t[e * 66 + sg + q * 4 + 0]) * rl[sg + q * 4 + 0];
    float f1 = bf2f(t[e * 66 + sg + q * 4 + 1]) * rl[sg + q * 4 + 1];
    float f2 = bf2f(t[e * 66 + sg + q * 4 + 2]) * rl[sg + q * 4 + 2];
    float f3 = bf2f(t[e * 66 + sg + q * 4 + 3]) * rl[sg + q * 4 + 3];
    int w0 = __builtin_amdgcn_cvt_pk_fp8_f32(f0, f1, 0, false);
    w0 = __builtin_amdgcn_cvt_pk_fp8_f32(f2, f3, w0, true);
    *(int*)(dst + q * 4) = w0;
  }
}

// Combine split-K bf16 partials + bias + residual, then LayerNorm. One block/row.
__global__ __launch_bounds__(256)
void ln_comb(const u16* __restrict__ p0, const u16* __restrict__ p1,
             const float* __restrict__ bias,
             const float* __restrict__ resf, const u16* __restrict__ resb,
             const float* __restrict__ gam, const float* __restrict__ bet,
             float* __restrict__ outf, u16* __restrict__ outb)
{
  long row = blockIdx.x;
  long base = (row << 10) + (threadIdx.x << 2);
  v4u16 a = *(const v4u16*)(p0 + base);
  v4u16 b = *(const v4u16*)(p1 + base);
  v4f bi = *(const v4f*)(bias + (threadIdx.x << 2));
  v4f v;
  v.x = bf2f(a.x) + bf2f(b.x) + bi.x;
  v.y = bf2f(a.y) + bf2f(b.y) + bi.y;
  v.z = bf2f(a.z) + bf2f(b.z) + bi.z;
  v.w = bf2f(a.w) + bf2f(b.w) + bi.w;
  if (resf) {
    v4f r = *(const v4f*)(resf + base);
    v.x += r.x; v.y += r.y; v.z += r.z; v.w += r.w;
  } else {
    v4u16 r = *(const v4u16*)(resb + base);
    v.x += bf2f(r.x); v.y += bf2f(r.y); v.z += bf2f(r.z); v.w += bf2f(r.w);
  }
  float s = v.x + v.y + v.z + v.w;
  float s2 = v.x * v.x + v.y * v.y + v.z * v.z + v.w * v.w;
#pragma unroll
  for (int o = 32; o > 0; o >>= 1) { s += __shfl_down(s, o); s2 += __shfl_down(s2, o); }
  __shared__ float red[8];
  int wv_ = threadIdx.x >> 6, ln = threadIdx.x & 63;
  if (ln == 0) { red[wv_] = s; red[4 + wv_] = s2; }
  __syncthreads();
  float S1 = red[0] + red[1] + red[2] + red[3];
  float S2 = red[4] + red[5] + red[6] + red[7];
  float mu = S1 * (1.f / 1024.f);
  float var = S2 * (1.f / 1024.f) - mu * mu;
  float rstd = rsqrtf(var + 1e-5f);
  v4f g4 = *(const v4f*)(gam + (threadIdx.x << 2));
  v4f b4 = *(const v4f*)(bet + (threadIdx.x << 2));
  v4f o4;
  o4.x = (v.x - mu) * rstd * g4.x + b4.x;
  o4.y = (v.y - mu) * rstd * g4.y + b4.y;
  o4.z = (v.z - mu) * rstd * g4.z + b4.z;
  o4.w = (v.w - mu) * rstd * g4.w + b4.w;
  if (outf) *(v4f*)(outf + base) = o4;
  if (outb) {
    v4u16 u;
    u.x = f2bf(o4.x); u.y = f2bf(o4.y); u.z = f2bf(o4.z); u.w = f2bf(o4.w);
    *(v4u16*)(outb + base) = u;
  }
}

// LayerNorm over 1024 cols; one block per row (fallback path).
__global__ __launch_bounds__(256)
void ln_kernel(const float* __restrict__ in, const float* __restrict__ gam,
               const float* __restrict__ bet, float* __restrict__ outf,
               u16* __restrict__ outb)
{
  long row = blockIdx.x;
  v4f v = *(const v4f*)(in + (row << 10) + (threadIdx.x << 2));
  float s = v.x + v.y + v.z + v.w;
  float s2 = v.x * v.x + v.y * v.y + v.z * v.z + v.w * v.w;
#pragma unroll
  for (int o = 32; o > 0; o >>= 1) { s += __shfl_down(s, o); s2 += __shfl_down(s2, o); }
  __shared__ float red[8];
  int wv_ = threadIdx.x >> 6, ln = threadIdx.x & 63;
  if (ln == 0) { red[wv_] = s; red[4 + wv_] = s2; }
  __syncthreads();
  float S1 = red[0] + red[1] + red[2] + red[3];
  float S2 = red[4] + red[5] + red[6] + red[7];
  float mu = S1 * (1.f / 1024.f);
  float var = S2 * (1.f / 1024.f) - mu * mu;
  float rstd = rsqrtf(var + 1e-5f);
  v4f g4 = *(const v4f*)(gam + (threadIdx.x << 2));
  v4f b4 = *(const v4f*)(bet + (threadIdx.x << 2));
  v4f o4;
  o4.x = (v.x - mu) * rstd * g4.x + b4.x;
  o4.y = (v.y - mu) * rstd * g4.y + b4.y;
  o4.z = (v.z - mu) * rstd * g4.z + b4.z;
  o4.w = (v.w - mu) * rstd * g4.w + b4.w;
  if (outf) *(v4f*)(outf + (row << 10) + (threadIdx.x << 2)) = o4;
  if (outb) {
    v4u16 u;
    u.x = f2bf(o4.x); u.y = f2bf(o4.y); u.z = f2bf(o4.z); u.w = f2bf(o4.w);
    *(v4u16*)(outb + (row << 10) + (threadIdx.x << 2)) = u;
  }
}

__global__ __launch_bounds__(256)
void cvt_bf16(const float* __restrict__ in, u16* __restrict__ out, int n4)
{
  int i = blockIdx.x * 256 + threadIdx.x;
  if (i >= n4) return;
  v4f v = ((const v4f*)in)[i];
  v4u16 u;
  u.x = f2bf(v.x); u.y = f2bf(v.y); u.z = f2bf(v.z); u.w = f2bf(v.w);
  ((v4u16*)out)[i] = u;
}

// Pack wq/wk/wv [h][d][e] -> B matrix [n = w*1024 + h*64 + e][d] bf16.
__global__ __launch_bounds__(256)
void pack_qkvw(const float* __restrict__ wq, const float* __restrict__ wk,
               const float* __restrict__ wv, u16* __restrict__ out)
{
  int i = blockIdx.x * 256 + threadIdx.x;  // 3*2^20 total
  int w = i >> 20, r = i & 1048575;
  int e = r & 63, d = (r >> 6) & 1023, h = r >> 16;
  const float* src = (w == 0) ? wq : ((w == 1) ? wk : wv);
  float v = src[(((long)h << 10) + d) * 64 + e];
  out[((((long)w << 10) + (h << 6) + e) << 10) + d] = f2bf(v);
}

// Detect whether mask is int32 (bytes at i%4!=0 all zero) or bool bytes.
__global__ void detect_mask_kernel(const unsigned char* __restrict__ m, int* __restrict__ flag)
{
  if (threadIdx.x == 0 && blockIdx.x == 0) {
    int nz = 0;
    for (int i = 0; i < 256; i++)
      if ((i & 3) != 0 && m[i] != 0) nz++;
    *flag = (nz == 0) ? 1 : 0;
  }
}

// Canonicalize mask into u8 {0,1} bytes (fallback path).
__global__ __launch_bounds__(256)
void canon_mask(const unsigned char* __restrict__ m, const int* __restrict__ flag,
                unsigned char* __restrict__ out)
{
  int i = blockIdx.x * 256 + threadIdx.x;
  uchar4 o;
  if (*flag) {
    const int* mi = (const int*)m;
    o.x = mi[i * 4 + 0] != 0; o.y = mi[i * 4 + 1] != 0;
    o.z = mi[i * 4 + 2] != 0; o.w = mi[i * 4 + 3] != 0;
  } else {
    o = ((const uchar4*)m)[i];
  }
  ((uchar4*)out)[i] = o;
}

// Bit-pack mask: out word g covers entries [32g, 32g+32), bit = entry&31.
__global__ __launch_bounds__(256)
void canon_pack(const unsigned char* __restrict__ m, const int* __restrict__ flag,
                unsigned int* __restrict__ out)
{
  int g = blockIdx.x * 256 + threadIdx.x;  // 262144 total
  unsigned int bits = 0;
  if (*flag) {
    const int* mi = (const int*)m + (long)g * 32;
#pragma unroll
    for (int i = 0; i < 32; i++) bits |= (mi[i] != 0 ? 1u : 0u) << i;
  } else {
    const unsigned char* mb = m + (long)g * 32;
#pragma unroll
    for (int i = 0; i < 32; i++) bits |= (mb[i] != 0 ? 1u : 0u) << i;
  }
  out[g] = bits;
}

extern "C" void kernel_launch(void* const* d_in, const int* in_sizes, int n_in,
                              void* d_out, int out_size, void* d_ws, size_t ws_size,
                              hipStream_t stream)
{
  const float* x     = (const float*)d_in[0];
  const unsigned char* mask = (const unsigned char*)d_in[1];
  const float* wq    = (const float*)d_in[2];
  const float* wk    = (const float*)d_in[3];
  const float* wv    = (const float*)d_in[4];
  const float* fc_w  = (const float*)d_in[5];
  const float* fc_b  = (const float*)d_in[6];
  const float* w1    = (const float*)d_in[7];
  const float* b1    = (const float*)d_in[8];
  const float* w2    = (const float*)d_in[9];
  const float* b2    = (const float*)d_in[10];
  const float* ln1_g = (const float*)d_in[11];
  const float* ln1_b = (const float*)d_in[12];
  const float* ln2_g = (const float*)d_in[13];
  const float* ln2_b = (const float*)d_in[14];
  (void)in_sizes; (void)n_in; (void)out_size;

  // ---- workspace map (aliased lifetimes) ----
  const size_t MB = 1ull << 20;
  char* ws = (char*)d_ws;
  int*   mflag = (int*)ws;                  // 4 B
  float* rc    = (float*)(ws + 65536);      // 512 KB (colsums)
  unsigned char* Mpk = (unsigned char*)(ws + 1 * MB);  // 1 MB bit-packed mask
  u16*   bqkv  = (u16*)(ws + 2 * MB);       // 6 MB
  u16*   fcb   = (u16*)(ws + 8 * MB);       // 2 MB
  u16*   w1b   = (u16*)(ws + 10 * MB);      // 8 MB
  u16*   w2b   = (u16*)(ws + 18 * MB);      // 8 MB
  u16*   xb    = (u16*)(ws + 26 * MB);      // 16 MB -> x1b alias
  u16*   x1b   = xb;
  u16*   Qb    = (u16*)(ws + 42 * MB);      // 16 MB
  u16*   Kb    = (u16*)(ws + 58 * MB);      // 16 MB
  u16*   Vb    = (u16*)(ws + 74 * MB);      // 16 MB ([z,s,e])
  u16*   vT    = (u16*)(ws + 90 * MB);      // 16 MB bf16 (fallback) / fp8 vT8 (main, 8 MB)
  unsigned char* vT8 = (unsigned char*)(ws + 90 * MB);
  u16*   oc    = (u16*)(ws + 106 * MB);     // 16 MB
  u16*   h1    = (u16*)(ws + 42 * MB);      // 64 MB alias Qb..vT (post-attention)
  float* r1    = (float*)(ws + 122 * MB);   // 32 MB (fallback path only)
  unsigned char* Mb = (unsigned char*)(ws + 122 * MB);  // 8 MB (fallback attn)
  unsigned char* E8 = (unsigned char*)(ws + 122 * MB);  // CZ MB fp8 E (aliases r1)
  u16*   p0    = (u16*)(ws + 122 * MB);     // 16 MB bf16 split-K partial (post-attn)
  u16*   p1    = (u16*)(ws + 138 * MB);     // 16 MB bf16 split-K partial

  // chunk tier: peak = 122 MB + CZ MB (fp8 E); split-K needs >=154 MB
  int CZ = 0;
  if      (ws_size >= 250 * MB) CZ = 128;
  else if (ws_size >= 186 * MB) CZ = 64;
  else if (ws_size >= 154 * MB) CZ = 32;

  detect_mask_kernel<<<1, 64, 0, stream>>>(mask, mflag);
  if (CZ > 0) canon_pack<<<1024, 256, 0, stream>>>(mask, mflag, (unsigned int*)Mpk);
  else        canon_mask<<<8192, 256, 0, stream>>>(mask, mflag, Mb);

  cvt_bf16<<<8192, 256, 0, stream>>>(x, xb, 2097152);
  pack_qkvw<<<12288, 256, 0, stream>>>(wq, wk, wv, bqkv);
  cvt_bf16<<<1024, 256, 0, stream>>>(fc_w, fcb, 262144);
  cvt_bf16<<<4096, 256, 0, stream>>>(w1, w1b, 1048576);
  cvt_bf16<<<4096, 256, 0, stream>>>(w2, w2b, 1048576);

  // QKV projections: [8192 x 1024] x [3072 x 1024]^T ; tiles 24x64
  {
    EpArgs ep = {};
    ep.q = Qb; ep.k = Kb; ep.v = Vb;
    gemm_nt<128, 128, 4, 4, MODE_QKV><<<dim3(24 * 64, 1), 256, 0, stream>>>(
        xb, 1024, 0, bqkv, 1024, 0, 1024, 3072, 24, 64, ep);
  }

  hipMemsetAsync(rc, 0, 128 * 1024 * 4, stream);
  if (CZ > 0) {
    for (int z0 = 0; z0 < 128; z0 += CZ) {
      attn_score<<<dim3(8, 8, CZ), 256, 0, stream>>>(
          Qb + (long)z0 * 65536, Kb + (long)z0 * 65536, Mpk,
          rc + (long)z0 * 1024, E8, z0);
      transpose_scale_fp8<<<dim3(16, CZ), 256, 0, stream>>>(
          Vb + (long)z0 * 65536, rc + (long)z0 * 1024, vT8 + (long)z0 * 65536);
      attn_pv_fp8<<<dim3(8, CZ), 256, 0, stream>>>(
          E8, vT8 + (long)z0 * 65536, oc, z0);
    }
  } else {
    attn_colsum<<<dim3(8, 128), 256, 0, stream>>>(Qb, Kb, Mb, rc);
    transpose_scale<<<dim3(16, 128), 256, 0, stream>>>(Vb, rc, vT);
    attn_pv<<<dim3(8, 128), 256, 0, stream>>>(Qb, Kb, vT, Mb, oc);
  }

  if (CZ > 0) {
    // proj split-K: K=1024 -> 2x512; bf16 partials; combine in LN1
    {
      EpArgs ep = {};
      ep.outb = p0; ep.outb2 = p1;
      gemm_nt<128, 128, 4, 4, MODE_PARTIAL><<<dim3(8 * 64, 2), 256, 0, stream>>>(
          oc, 1024, 512, fcb, 1024, 512, 512, 1024, 8, 64, ep);
    }
    ln_comb<<<8192, 256, 0, stream>>>(p0, p1, fc_b, x, (const u16*)nullptr,
                                      ln1_g, ln1_b, (float*)nullptr, x1b);
    {
      EpArgs ep = {};
      ep.bias = b1; ep.outb = h1;
      gemm_nt<128, 128, 4, 4, MODE_BIAS_RELU><<<dim3(32 * 64, 1), 256, 0, stream>>>(
          x1b, 1024, 0, w1b, 1024, 0, 1024, 4096, 32, 64, ep);
    }
    // MLP2 split-K: K=4096 -> 2x2048; combine + residual + LN2 -> d_out
    {
      EpArgs ep = {};
      ep.outb = p0; ep.outb2 = p1;
      gemm_nt<128, 128, 4, 4, MODE_PARTIAL><<<dim3(8 * 64, 2), 256, 0, stream>>>(
          h1, 4096, 2048, w2b, 4096, 2048, 2048, 1024, 8, 64, ep);
    }
    ln_comb<<<8192, 256, 0, stream>>>(p0, p1, b2, (const float*)nullptr, x1b,
                                      ln2_g, ln2_b, (float*)d_out, (u16*)nullptr);
  } else {
    {
      EpArgs ep = {};
      ep.bias = fc_b; ep.res = x; ep.outf = r1;
      gemm_nt<128, 128, 4, 4, MODE_BIAS_RES><<<dim3(8 * 64, 1), 256, 0, stream>>>(
          oc, 1024, 0, fcb, 1024, 0, 1024, 1024, 8, 64, ep);
    }
    ln_kernel<<<8192, 256, 0, stream>>>(r1, ln1_g, ln1_b, (float*)nullptr, x1b);
    {
      EpArgs ep = {};
      ep.bias = b1; ep.outb = h1;
      gemm_nt<128, 128, 4, 4, MODE_BIAS_RELU><<<dim3(32 * 64, 1), 256, 0, stream>>>(
          x1b, 1024, 0, w1b, 1024, 0, 1024, 4096, 32, 64, ep);
    }
    {
      EpArgs ep = {};
      ep.bias = b2; ep.res_bf = x1b; ep.outf = r1;
      gemm_nt<128, 128, 4, 4, MODE_BIAS_RES><<<dim3(8 * 64, 1), 256, 0, stream>>>(
          h1, 4096, 0, w2b, 4096, 0, 4096, 1024, 8, 64, ep);
    }
    ln_kernel<<<8192, 256, 0, stream>>>(r1, ln2_g, ln2_b, (float*)d_out, (u16*)nullptr);
  }
}